// Round 8
// baseline (1676.157 us; speedup 1.0000x reference)
//
#include <hip/hip_runtime.h>
#include <cstdint>
#include <cmath>

#define B_ 64
#define S_ 256
#define IN_ 32
#define D_ 512
#define H_ 8
#define L_ 2
#define DFF_ 2048
#define C_ 16
#define DH_ 64
#define NTOK (B_*S_)   // 16384
#define HALF_ 8192

typedef __attribute__((ext_vector_type(8))) short bf16x8;
typedef __attribute__((ext_vector_type(4))) float f32x4;
typedef __attribute__((ext_vector_type(8))) ushort ushortx8;

__device__ __forceinline__ ushort bf16_rn(float x) {
    union { float f; uint32_t u; } v; v.f = x;
    uint32_t r = v.u + 0x7fffu + ((v.u >> 16) & 1u);
    return (ushort)(r >> 16);
}
__device__ __forceinline__ float bf16_f32(ushort h) {
    union { uint32_t u; float f; } v; v.u = ((uint32_t)h) << 16;
    return v.f;
}

#define GLDS(gp, lp) __builtin_amdgcn_global_load_lds( \
    (const __attribute__((address_space(1))) void*)(gp), \
    (__attribute__((address_space(3))) void*)(lp), 16, 0, 0)

// XCD-chunk bijective swizzle (nwg % 8 == 0 for all users).
__device__ __forceinline__ int xcd_swz(int lid, int nwg) {
    return (lid & 7) * (nwg >> 3) + (lid >> 3);
}

// ---------------------------------------------------------------------------
// 8-phase 256x256 bf16x3 GEMM (m201 template adapted): 3 sequential segments
// (Ahi*Bhi, Ahi*Blo, Alo*Bhi), BK=64, 512 threads (8 waves, 2Mx4N), per-wave
// output 128x64 (8x4 16x16 frags). LDS 128 KiB dbuf; slot-XOR swizzle
// slot^=(row&7) applied on BOTH the pre-swizzled global source and ds_read.
// Per iteration (1 K-tile): 4 phases of {GLDS part prefetch | ds_read quadrant
// | barrier | lgkmcnt(0) | setprio(1) 16 MFMA setprio(0) | barrier}; tile
// confirm = own vmcnt(2) + barrier at phase 0 only (never drains mid-loop).
// MODE: 3 = split hi/lo out + ReLU (FFN1 use).
// ---------------------------------------------------------------------------
template<int MODE>
__global__ __launch_bounds__(512)
void gemm3_8p(const ushort* __restrict__ Ahi, const ushort* __restrict__ Alo,
              const ushort* __restrict__ Bhi, const ushort* __restrict__ Blo,
              const float* __restrict__ bias,
              float* __restrict__ Cf, ushort* __restrict__ Chi, ushort* __restrict__ Clo,
              int M, int N, int K)
{
    __shared__ __align__(16) ushort Als[2][2][128*64];   // [dbuf][half][row*64+col]
    __shared__ __align__(16) ushort Bls[2][2][128*64];
    const int tid = threadIdx.x, wave = tid >> 6, lane = tid & 63;
    const int nwg = gridDim.x * gridDim.y;
    const int swz = xcd_swz(blockIdx.y * gridDim.x + blockIdx.x, nwg);
    const int m0 = (swz / gridDim.x) << 8, n0 = (swz % gridDim.x) << 8;
    const int wr = wave >> 2, wc = wave & 3;

    const ushort* Ahp = Ahi + (size_t)m0 * K;
    const ushort* Alp = Alo + (size_t)m0 * K;
    const ushort* Bhp = Bhi + (size_t)n0 * K;
    const ushort* Blp = Blo + (size_t)n0 * K;

    const int KT = K >> 6;       // K-tiles per segment
    const int NT = 3 * KT;

    f32x4 acc[8][4];
    #pragma unroll
    for (int m = 0; m < 8; ++m)
        #pragma unroll
        for (int n = 0; n < 4; ++n)
            acc[m][n] = (f32x4){0.f, 0.f, 0.f, 0.f};

    // part 0/1: A half 0/1; part 2/3: B half 0/1. 2 GLDS per part per wave.
    auto stage_part = [&](int buf, const ushort* Asrc, const ushort* Bsrc,
                          int kk, int part) {
        const int hf = part & 1;
        const ushort* src = (part < 2) ? Asrc : Bsrc;
        ushort* dstbase = (part < 2) ? &Als[buf][hf][0] : &Bls[buf][hf][0];
        #pragma unroll
        for (int j = 0; j < 2; ++j) {
            const int rl   = wave * 16 + j * 8 + (lane >> 3);     // 0..127
            const int slot = (lane & 7) ^ (rl & 7);
            GLDS(src + (size_t)(hf * 128 + rl) * K + kk + slot * 8,
                 dstbase + (wave * 16 + j * 8) * 64);
        }
    };

    // prologue: fully stage tile 0 into buf 0
    #pragma unroll
    for (int part = 0; part < 4; ++part)
        stage_part(0, Ahp, Bhp, 0, part);

    int seg = 0, kt = 0;
    for (int g = 0; g < NT; ++g) {
        const int buf = g & 1;
        int nseg = seg, nkt = kt + 1;
        if (nkt == KT) { nkt = 0; nseg = seg + 1; }
        const ushort* An = (nseg == 2) ? Alp : Ahp;
        const ushort* Bn = (nseg == 1) ? Blp : Bhp;
        const bool more = (g + 1 < NT);

        bf16x8 bfr[4][2];
        #pragma unroll
        for (int p = 0; p < 4; ++p) {
            if (more) stage_part(buf ^ 1, An, Bn, nkt << 6, p);
            if (p == 0) {
                if (more) asm volatile("s_waitcnt vmcnt(2)" ::: "memory");
                else      asm volatile("s_waitcnt vmcnt(0)" ::: "memory");
                __builtin_amdgcn_sched_barrier(0);
                __builtin_amdgcn_s_barrier();          // tile g landed, all waves
                // read all 8 B fragments (held in regs across phases)
                #pragma unroll
                for (int nj = 0; nj < 4; ++nj) {
                    const int gr = wc * 64 + nj * 16;
                    const int hb2 = gr >> 7;
                    const int rl = (gr & 127) + (lane & 15);
                    #pragma unroll
                    for (int ks = 0; ks < 2; ++ks) {
                        const int es = (ks * 4 + (lane >> 4)) ^ (lane & 7);
                        bfr[nj][ks] = *(const bf16x8*)&Bls[buf][hb2][rl * 64 + es * 8];
                    }
                }
            }
            // read A quadrant: mi = 2p, 2p+1
            bf16x8 a0[2], a1[2];
            {
                const int r0 = (2 * p) * 16 + (lane & 15);
                const int r1 = (2 * p + 1) * 16 + (lane & 15);
                #pragma unroll
                for (int ks = 0; ks < 2; ++ks) {
                    const int es = (ks * 4 + (lane >> 4)) ^ (lane & 7);
                    a0[ks] = *(const bf16x8*)&Als[buf][wr][r0 * 64 + es * 8];
                    a1[ks] = *(const bf16x8*)&Als[buf][wr][r1 * 64 + es * 8];
                }
            }
            __builtin_amdgcn_sched_barrier(0);
            __builtin_amdgcn_s_barrier();
            asm volatile("s_waitcnt lgkmcnt(0)" ::: "memory");
            __builtin_amdgcn_sched_barrier(0);
            __builtin_amdgcn_s_setprio(1);
            #pragma unroll
            for (int ks = 0; ks < 2; ++ks)
                #pragma unroll
                for (int nj = 0; nj < 4; ++nj) {
                    acc[2*p][nj]   = __builtin_amdgcn_mfma_f32_16x16x32_bf16(a0[ks], bfr[nj][ks], acc[2*p][nj],   0, 0, 0);
                    acc[2*p+1][nj] = __builtin_amdgcn_mfma_f32_16x16x32_bf16(a1[ks], bfr[nj][ks], acc[2*p+1][nj], 0, 0, 0);
                }
            __builtin_amdgcn_s_setprio(0);
            __builtin_amdgcn_sched_barrier(0);
            __builtin_amdgcn_s_barrier();
        }
        seg = nseg; kt = nkt;
    }

    const int col_l = lane & 15;
    float bv[4];
    #pragma unroll
    for (int nj = 0; nj < 4; ++nj) bv[nj] = bias[n0 + wc * 64 + nj * 16 + col_l];
    #pragma unroll
    for (int mi = 0; mi < 8; ++mi) {
        #pragma unroll
        for (int jj = 0; jj < 4; ++jj) {
            const size_t grow = (size_t)(m0 + wr * 128 + mi * 16 + (lane >> 4) * 4 + jj);
            #pragma unroll
            for (int nj = 0; nj < 4; ++nj) {
                float x = acc[mi][nj][jj] + bv[nj];
                if (MODE & 1) x = fmaxf(x, 0.f);
                const size_t gidx = grow * N + (n0 + wc * 64 + nj * 16 + col_l);
                if (MODE < 2) {
                    Cf[gidx] = x;
                } else {
                    ushort hb = bf16_rn(x);
                    Chi[gidx] = hb;
                    Clo[gidx] = bf16_rn(x - bf16_f32(hb));
                }
            }
        }
    }
}

// ---------------------------------------------------------------------------
// Merged bf16x3 GEMM (128x128, 2-phase, counted vmcnt) — round-6 kernel,
// used for all GEMMs whose grids under-fill 256^2 tiles.
// MODE: 0 = f32 out, 2 = split hi/lo out, 3 = split + ReLU.
// ---------------------------------------------------------------------------
template<int MODE>
__global__ __launch_bounds__(256)
void gemm3(const ushort* __restrict__ Ahi, const ushort* __restrict__ Alo,
           const ushort* __restrict__ Bhi, const ushort* __restrict__ Blo,
           const float* __restrict__ bias,
           float* __restrict__ Cf, ushort* __restrict__ Chi, ushort* __restrict__ Clo,
           int M, int N, int K)
{
    __shared__ __align__(16) ushort Als[2][2][128*32];
    __shared__ __align__(16) ushort Bls[2][2][128*32];
    const int tid  = threadIdx.x;
    const int wave = tid >> 6, lane = tid & 63;
    const int nwg = gridDim.x * gridDim.y;
    const int swz = xcd_swz(blockIdx.y * gridDim.x + blockIdx.x, nwg);
    const int m0 = (swz / gridDim.x) << 7, n0 = (swz % gridDim.x) << 7;
    const int wr = wave >> 1, wc = wave & 1;

    const ushort* Ah = Ahi + (size_t)m0 * K;
    const ushort* Al = Alo + (size_t)m0 * K;
    const ushort* Bh = Bhi + (size_t)n0 * K;
    const ushort* Bl = Blo + (size_t)n0 * K;

    const int KT = K >> 5;

    f32x4 acc[4][4];
    #pragma unroll
    for (int m = 0; m < 4; ++m)
        #pragma unroll
        for (int n = 0; n < 4; ++n)
            acc[m][n] = (f32x4){0.f, 0.f, 0.f, 0.f};

    auto stage = [&](int buf, int kk) {
        #pragma unroll
        for (int i = 0; i < 2; ++i) {
            const int rbase = wave * 32 + i * 16;
            const int row   = rbase + (lane >> 2);
            const int slot  = (lane & 3) ^ ((row >> 1) & 3);
            GLDS(Ah + (size_t)row * K + kk + slot * 8, &Als[buf][0][rbase * 32]);
            GLDS(Al + (size_t)row * K + kk + slot * 8, &Als[buf][1][rbase * 32]);
            GLDS(Bh + (size_t)row * K + kk + slot * 8, &Bls[buf][0][rbase * 32]);
            GLDS(Bl + (size_t)row * K + kk + slot * 8, &Bls[buf][1][rbase * 32]);
        }
    };

    stage(0, 0);
    for (int t = 0; t < KT; ++t) {
        const int buf = t & 1;
        if (t + 1 < KT) {
            stage(buf ^ 1, (t + 1) << 5);
            asm volatile("s_waitcnt vmcnt(8)" ::: "memory");
        } else {
            asm volatile("s_waitcnt vmcnt(0)" ::: "memory");
        }
        __builtin_amdgcn_sched_barrier(0);
        __builtin_amdgcn_s_barrier();

        const int chunk = lane >> 4;
        bf16x8 afh[4], afl[4], bfh[4], bfl[4];
        #pragma unroll
        for (int m = 0; m < 4; ++m) {
            const int row = wr * 64 + m * 16 + (lane & 15);
            const int sl  = chunk ^ ((row >> 1) & 3);
            afh[m] = *(const bf16x8*)(&Als[buf][0][row * 32 + sl * 8]);
            afl[m] = *(const bf16x8*)(&Als[buf][1][row * 32 + sl * 8]);
        }
        #pragma unroll
        for (int n = 0; n < 4; ++n) {
            const int row = wc * 64 + n * 16 + (lane & 15);
            const int sl  = chunk ^ ((row >> 1) & 3);
            bfh[n] = *(const bf16x8*)(&Bls[buf][0][row * 32 + sl * 8]);
            bfl[n] = *(const bf16x8*)(&Bls[buf][1][row * 32 + sl * 8]);
        }
        #pragma unroll
        for (int m = 0; m < 4; ++m)
            #pragma unroll
            for (int n = 0; n < 4; ++n) {
                acc[m][n] = __builtin_amdgcn_mfma_f32_16x16x32_bf16(afh[m], bfh[n], acc[m][n], 0, 0, 0);
                acc[m][n] = __builtin_amdgcn_mfma_f32_16x16x32_bf16(afh[m], bfl[n], acc[m][n], 0, 0, 0);
                acc[m][n] = __builtin_amdgcn_mfma_f32_16x16x32_bf16(afl[m], bfh[n], acc[m][n], 0, 0, 0);
            }
        __builtin_amdgcn_sched_barrier(0);
        __builtin_amdgcn_s_barrier();
    }

    const int col_l = lane & 15;
    float bv[4];
    #pragma unroll
    for (int n = 0; n < 4; ++n) bv[n] = bias[n0 + wc * 64 + n * 16 + col_l];
    #pragma unroll
    for (int m = 0; m < 4; ++m) {
        #pragma unroll
        for (int j = 0; j < 4; ++j) {
            const size_t grow = (size_t)(m0 + wr * 64 + m * 16 + (lane >> 4) * 4 + j);
            #pragma unroll
            for (int n = 0; n < 4; ++n) {
                float x = acc[m][n][j] + bv[n];
                if (MODE & 1) x = fmaxf(x, 0.f);
                const size_t gidx = grow * N + (n0 + wc * 64 + n * 16 + col_l);
                if (MODE < 2) {
                    Cf[gidx] = x;
                } else {
                    ushort hb = bf16_rn(x);
                    Chi[gidx] = hb;
                    Clo[gidx] = bf16_rn(x - bf16_f32(hb));
                }
            }
        }
    }
}

// ---------------------------------------------------------------------------
// Batched QK^T: S[bh][q][k] = 0.125 * Q_bh . K_bh^T  (bf16x3, merged staging)
// ---------------------------------------------------------------------------
__global__ __launch_bounds__(256)
void qk_gemm(const ushort* __restrict__ qkvhi, const ushort* __restrict__ qkvlo,
             float* __restrict__ S)
{
    __shared__ __align__(16) ushort Als[2][2][128*32];
    __shared__ __align__(16) ushort Bls[2][2][128*32];
    const int tid = threadIdx.x, wave = tid >> 6, lane = tid & 63;
    const int swz = xcd_swz(blockIdx.y * 4 + blockIdx.x, 512);
    const int bh = swz >> 2;
    const int qt = (swz >> 1) & 1, kt = swz & 1;
    const int b = bh >> 3, h = bh & 7;
    const ushort* Ah = qkvhi + ((size_t)(b * 256 + qt * 128)) * 1536 + h * 64;
    const ushort* Al = qkvlo + ((size_t)(b * 256 + qt * 128)) * 1536 + h * 64;
    const ushort* Bh = qkvhi + ((size_t)(b * 256 + kt * 128)) * 1536 + 512 + h * 64;
    const ushort* Bl = qkvlo + ((size_t)(b * 256 + kt * 128)) * 1536 + 512 + h * 64;
    const int wr = wave >> 1, wc = wave & 1;

    f32x4 acc[4][4];
    #pragma unroll
    for (int m = 0; m < 4; ++m)
        #pragma unroll
        for (int n = 0; n < 4; ++n)
            acc[m][n] = (f32x4){0.f, 0.f, 0.f, 0.f};

    auto stage = [&](int buf, int kk) {
        #pragma unroll
        for (int i = 0; i < 2; ++i) {
            const int rbase = wave * 32 + i * 16;
            const int row   = rbase + (lane >> 2);
            const int slot  = (lane & 3) ^ ((row >> 1) & 3);
            GLDS(Ah + (size_t)row * 1536 + kk + slot * 8, &Als[buf][0][rbase * 32]);
            GLDS(Al + (size_t)row * 1536 + kk + slot * 8, &Als[buf][1][rbase * 32]);
            GLDS(Bh + (size_t)row * 1536 + kk + slot * 8, &Bls[buf][0][rbase * 32]);
            GLDS(Bl + (size_t)row * 1536 + kk + slot * 8, &Bls[buf][1][rbase * 32]);
        }
    };

    stage(0, 0);
    #pragma unroll
    for (int t = 0; t < 2; ++t) {
        __syncthreads();
        if (t == 0) stage(1, 32);
        const int chunk = lane >> 4;
        bf16x8 afh[4], afl[4], bfh[4], bfl[4];
        #pragma unroll
        for (int m = 0; m < 4; ++m) {
            const int row = wr * 64 + m * 16 + (lane & 15);
            const int sl  = chunk ^ ((row >> 1) & 3);
            afh[m] = *(const bf16x8*)(&Als[t][0][row * 32 + sl * 8]);
            afl[m] = *(const bf16x8*)(&Als[t][1][row * 32 + sl * 8]);
        }
        #pragma unroll
        for (int n = 0; n < 4; ++n) {
            const int row = wc * 64 + n * 16 + (lane & 15);
            const int sl  = chunk ^ ((row >> 1) & 3);
            bfh[n] = *(const bf16x8*)(&Bls[t][0][row * 32 + sl * 8]);
            bfl[n] = *(const bf16x8*)(&Bls[t][1][row * 32 + sl * 8]);
        }
        #pragma unroll
        for (int m = 0; m < 4; ++m)
            #pragma unroll
            for (int n = 0; n < 4; ++n) {
                acc[m][n] = __builtin_amdgcn_mfma_f32_16x16x32_bf16(afh[m], bfh[n], acc[m][n], 0, 0, 0);
                acc[m][n] = __builtin_amdgcn_mfma_f32_16x16x32_bf16(afh[m], bfl[n], acc[m][n], 0, 0, 0);
                acc[m][n] = __builtin_amdgcn_mfma_f32_16x16x32_bf16(afl[m], bfh[n], acc[m][n], 0, 0, 0);
            }
        __syncthreads();
    }

    const int col_l = lane & 15;
    #pragma unroll
    for (int m = 0; m < 4; ++m)
        #pragma unroll
        for (int j = 0; j < 4; ++j) {
            const int row = qt * 128 + wr * 64 + m * 16 + (lane >> 4) * 4 + j;
            #pragma unroll
            for (int n = 0; n < 4; ++n) {
                const int col = kt * 128 + wc * 64 + n * 16 + col_l;
                S[(size_t)bh * 65536 + (size_t)row * 256 + col] = acc[m][n][j] * 0.125f;
            }
        }
}

// ---------------------------------------------------------------------------
__global__ __launch_bounds__(256)
void softmax_p(const float* __restrict__ S, ushort* __restrict__ Phi,
               ushort* __restrict__ Plo)
{
    const int row = blockIdx.x * 4 + (threadIdx.x >> 6);
    const int lane = threadIdx.x & 63;
    float4 v = *(const float4*)(S + (size_t)row * 256 + lane * 4);
    float mx = fmaxf(fmaxf(v.x, v.y), fmaxf(v.z, v.w));
    #pragma unroll
    for (int d = 1; d < 64; d <<= 1) mx = fmaxf(mx, __shfl_xor(mx, d));
    float e0 = expf(v.x - mx), e1 = expf(v.y - mx);
    float e2 = expf(v.z - mx), e3 = expf(v.w - mx);
    float s = (e0 + e1) + (e2 + e3);
    #pragma unroll
    for (int d = 1; d < 64; d <<= 1) s += __shfl_xor(s, d);
    const float inv = 1.0f / s;
    float p0 = e0 * inv, p1 = e1 * inv, p2 = e2 * inv, p3 = e3 * inv;
    ushort4 hh, ll;
    hh.x = bf16_rn(p0); ll.x = bf16_rn(p0 - bf16_f32(hh.x));
    hh.y = bf16_rn(p1); ll.y = bf16_rn(p1 - bf16_f32(hh.y));
    hh.z = bf16_rn(p2); ll.z = bf16_rn(p2 - bf16_f32(hh.z));
    hh.w = bf16_rn(p3); ll.w = bf16_rn(p3 - bf16_f32(hh.w));
    *(ushort4*)(Phi + (size_t)row * 256 + lane * 4) = hh;
    *(ushort4*)(Plo + (size_t)row * 256 + lane * 4) = ll;
}

// ---------------------------------------------------------------------------
__global__ __launch_bounds__(256)
void vtrans(const ushort* __restrict__ qkvhi, const ushort* __restrict__ qkvlo,
            ushort* __restrict__ VThi, ushort* __restrict__ VTlo)
{
    __shared__ ushort T[64][272];
    const int bh = blockIdx.x;
    const int b = bh >> 3, h = bh & 7;
    const int tid = threadIdx.x;
    #pragma unroll
    for (int pass = 0; pass < 2; ++pass) {
        const ushort* src = pass ? qkvlo : qkvhi;
        ushort* dst = pass ? VTlo : VThi;
        const ushort* p = src + ((size_t)b * 256 + tid) * 1536 + 1024 + h * 64;
        #pragma unroll
        for (int i = 0; i < 8; ++i) {
            ushortx8 v = *(const ushortx8*)(p + i * 8);
            #pragma unroll
            for (int j = 0; j < 8; ++j) T[i * 8 + j][tid] = v[j];
        }
        __syncthreads();
        const int dh = tid >> 2, k0 = (tid & 3) * 64;
        ushort* op = dst + ((size_t)bh * 64 + dh) * 256 + k0;
        #pragma unroll
        for (int i = 0; i < 8; ++i)
            *(ushortx8*)(op + i * 8) = *(const ushortx8*)&T[dh][k0 + i * 8];
        __syncthreads();
    }
}

// ---------------------------------------------------------------------------
__global__ __launch_bounds__(256)
void pv_gemm(const ushort* __restrict__ Phi, const ushort* __restrict__ Plo,
             const ushort* __restrict__ VThi, const ushort* __restrict__ VTlo,
             ushort* __restrict__ obhi, ushort* __restrict__ oblo, int t0)
{
    __shared__ __align__(16) ushort Als[2][2][128*32];
    __shared__ __align__(16) ushort Bls[2][2][64*32];
    const int tid = threadIdx.x, wave = tid >> 6, lane = tid & 63;
    const int swz = xcd_swz(blockIdx.y * 2 + blockIdx.x, 256);
    const int bh = swz >> 1, qt = swz & 1;
    const ushort* Ah = Phi + ((size_t)bh * 256 + qt * 128) * 256;
    const ushort* Al = Plo + ((size_t)bh * 256 + qt * 128) * 256;
    const ushort* Bh = VThi + (size_t)bh * 64 * 256;
    const ushort* Bl = VTlo + (size_t)bh * 64 * 256;

    f32x4 acc[2][4];
    #pragma unroll
    for (int m = 0; m < 2; ++m)
        #pragma unroll
        for (int n = 0; n < 4; ++n)
            acc[m][n] = (f32x4){0.f, 0.f, 0.f, 0.f};

    auto stage = [&](int buf, int kk) {
        #pragma unroll
        for (int i = 0; i < 2; ++i) {
            const int rbase = wave * 32 + i * 16;
            const int row   = rbase + (lane >> 2);
            const int slot  = (lane & 3) ^ ((row >> 1) & 3);
            GLDS(Ah + (size_t)row * 256 + kk + slot * 8, &Als[buf][0][rbase * 32]);
            GLDS(Al + (size_t)row * 256 + kk + slot * 8, &Als[buf][1][rbase * 32]);
        }
        const int rbase2 = wave * 16;
        const int row2   = rbase2 + (lane >> 2);
        const int slot2  = (lane & 3) ^ ((row2 >> 1) & 3);
        GLDS(Bh + (size_t)row2 * 256 + kk + slot2 * 8, &Bls[buf][0][rbase2 * 32]);
        GLDS(Bl + (size_t)row2 * 256 + kk + slot2 * 8, &Bls[buf][1][rbase2 * 32]);
    };

    stage(0, 0);
    for (int t = 0; t < 8; ++t) {
        const int buf = t & 1;
        __syncthreads();
        if (t < 7) stage(buf ^ 1, (t + 1) << 5);
        const int chunk = lane >> 4;
        bf16x8 afh[2], afl[2], bfh[4], bfl[4];
        #pragma unroll
        for (int m = 0; m < 2; ++m) {
            const int row = wave * 32 + m * 16 + (lane & 15);
            const int sl  = chunk ^ ((row >> 1) & 3);
            afh[m] = *(const bf16x8*)(&Als[buf][0][row * 32 + sl * 8]);
            afl[m] = *(const bf16x8*)(&Als[buf][1][row * 32 + sl * 8]);
        }
        #pragma unroll
        for (int n = 0; n < 4; ++n) {
            const int row = n * 16 + (lane & 15);
            const int sl  = chunk ^ ((row >> 1) & 3);
            bfh[n] = *(const bf16x8*)(&Bls[buf][0][row * 32 + sl * 8]);
            bfl[n] = *(const bf16x8*)(&Bls[buf][1][row * 32 + sl * 8]);
        }
        #pragma unroll
        for (int m = 0; m < 2; ++m)
            #pragma unroll
            for (int n = 0; n < 4; ++n) {
                acc[m][n] = __builtin_amdgcn_mfma_f32_16x16x32_bf16(afh[m], bfh[n], acc[m][n], 0, 0, 0);
                acc[m][n] = __builtin_amdgcn_mfma_f32_16x16x32_bf16(afh[m], bfl[n], acc[m][n], 0, 0, 0);
                acc[m][n] = __builtin_amdgcn_mfma_f32_16x16x32_bf16(afl[m], bfh[n], acc[m][n], 0, 0, 0);
            }
        __syncthreads();
    }

    const int b = bh >> 3, h = bh & 7;
    const int col_l = lane & 15;
    #pragma unroll
    for (int m = 0; m < 2; ++m)
        #pragma unroll
        for (int j = 0; j < 4; ++j) {
            const int q = qt * 128 + wave * 32 + m * 16 + (lane >> 4) * 4 + j;
            const size_t token = (size_t)t0 + (size_t)b * 256 + q;
            #pragma unroll
            for (int n = 0; n < 4; ++n) {
                const int col = h * 64 + n * 16 + col_l;
                float x = acc[m][n][j];
                ushort hb = bf16_rn(x);
                obhi[token * 512 + col] = hb;
                oblo[token * 512 + col] = bf16_rn(x - bf16_f32(hb));
            }
        }
}

// ---------------------------------------------------------------------------
__global__ __launch_bounds__(256)
void gemm_f32(const float* __restrict__ A, const float* __restrict__ W,
              const float* __restrict__ bias, float* __restrict__ Cc,
              ushort* __restrict__ Chi, ushort* __restrict__ Clo,
              int M, int N, int K)
{
    __shared__ float As[16][68];
    __shared__ float Bs[16][64];
    const int tid = threadIdx.x;
    const int tx = tid & 15, ty = tid >> 4;
    const int m0 = blockIdx.y << 6, n0 = blockIdx.x << 6;
    const int arow = tid >> 2, ak4 = (tid & 3) << 2;
    const int brow = tid >> 4, bc4 = (tid & 15) << 2;
    float acc[4][4] = {};
    const float* aptr = A + (size_t)(m0 + arow) * K + ak4;
    const float* bptr = W + (size_t)brow * N + n0 + bc4;
    for (int k0 = 0; k0 < K; k0 += 16) {
        float4 av = *(const float4*)(aptr + k0);
        float4 bv = *(const float4*)(bptr + (size_t)k0 * N);
        __syncthreads();
        As[ak4+0][arow] = av.x; As[ak4+1][arow] = av.y;
        As[ak4+2][arow] = av.z; As[ak4+3][arow] = av.w;
        *(float4*)&Bs[brow][bc4] = bv;
        __syncthreads();
        #pragma unroll
        for (int kk = 0; kk < 16; ++kk) {
            float4 a = *(const float4*)&As[kk][ty << 2];
            float4 b = *(const float4*)&Bs[kk][tx << 2];
            float ar[4] = {a.x,a.y,a.z,a.w};
            float br[4] = {b.x,b.y,b.z,b.w};
            #pragma unroll
            for (int i = 0; i < 4; ++i)
                #pragma unroll
                for (int j = 0; j < 4; ++j)
                    acc[i][j] = fmaf(ar[i], br[j], acc[i][j]);
        }
    }
    float4 bb = *(const float4*)(bias + n0 + (tx << 2));
    #pragma unroll
    for (int i = 0; i < 4; ++i) {
        int m = m0 + (ty << 2) + i;
        float o[4];
        o[0] = acc[i][0] + bb.x; o[1] = acc[i][1] + bb.y;
        o[2] = acc[i][2] + bb.z; o[3] = acc[i][3] + bb.w;
        ushort4 hh, ll;
        hh.x = bf16_rn(o[0]); ll.x = bf16_rn(o[0] - bf16_f32(hh.x));
        hh.y = bf16_rn(o[1]); ll.y = bf16_rn(o[1] - bf16_f32(hh.y));
        hh.z = bf16_rn(o[2]); ll.z = bf16_rn(o[2] - bf16_f32(hh.z));
        hh.w = bf16_rn(o[3]); ll.w = bf16_rn(o[3] - bf16_f32(hh.w));
        const size_t base = (size_t)m * N + n0 + (tx << 2);
        *(float4*)(Cc + base) = (float4){o[0],o[1],o[2],o[3]};
        *(ushort4*)(Chi + base) = hh;
        *(ushort4*)(Clo + base) = ll;
    }
}

__global__ __launch_bounds__(256)
void transpose_split(const float* __restrict__ W, ushort* __restrict__ Thi,
                     ushort* __restrict__ Tlo, int K, int N)
{
    __shared__ float T[64][65];
    const int k0 = blockIdx.y << 6, n0 = blockIdx.x << 6;
    const int tid = threadIdx.x;
    #pragma unroll
    for (int i = 0; i < 16; ++i) {
        int idx = tid + i * 256;
        int kl = idx >> 6, nl = idx & 63;
        T[nl][kl] = W[(size_t)(k0 + kl) * N + n0 + nl];
    }
    __syncthreads();
    #pragma unroll
    for (int i = 0; i < 16; ++i) {
        int idx = tid + i * 256;
        int nl = idx >> 6, kl = idx & 63;
        float x = T[nl][kl];
        ushort hb = bf16_rn(x);
        size_t o = (size_t)(n0 + nl) * K + k0 + kl;
        Thi[o] = hb;
        Tlo[o] = bf16_rn(x - bf16_f32(hb));
    }
}

__global__ __launch_bounds__(256)
void concat3(const float* __restrict__ a, const float* __restrict__ b,
             const float* __restrict__ c, float* __restrict__ out)
{
    int i = blockIdx.x * 256 + threadIdx.x;
    out[i] = (i < 512) ? a[i] : (i < 1024 ? b[i - 512] : c[i - 1024]);
}

// ---------------------------------------------------------------------------
__global__ __launch_bounds__(64)
void ln_res(float* __restrict__ h, const float* __restrict__ t,
            const float* __restrict__ sc, const float* __restrict__ bi,
            ushort* __restrict__ hhi, ushort* __restrict__ hlo)
{
    const int row = blockIdx.x, lane = threadIdx.x;
    const size_t off = (size_t)row * D_ + (size_t)lane * 8;
    float x[8];
    float4 a0 = *(const float4*)(h + off),  a1 = *(const float4*)(h + off + 4);
    float4 b0 = *(const float4*)(t + off),  b1 = *(const float4*)(t + off + 4);
    x[0]=a0.x+b0.x; x[1]=a0.y+b0.y; x[2]=a0.z+b0.z; x[3]=a0.w+b0.w;
    x[4]=a1.x+b1.x; x[5]=a1.y+b1.y; x[6]=a1.z+b1.z; x[7]=a1.w+b1.w;

    float s = 0.f;
    #pragma unroll
    for (int i = 0; i < 8; ++i) s += x[i];
    #pragma unroll
    for (int d = 1; d < 64; d <<= 1) s += __shfl_xor(s, d);
    float mean = s * (1.0f / 512.0f);

    float vsum = 0.f;
    #pragma unroll
    for (int i = 0; i < 8; ++i) { float dx = x[i] - mean; vsum += dx * dx; }
    #pragma unroll
    for (int d = 1; d < 64; d <<= 1) vsum += __shfl_xor(vsum, d);
    float den = sqrtf(vsum * (1.0f / 512.0f) + 1e-5f);

    float4 s0 = *(const float4*)(sc + lane*8), s1 = *(const float4*)(sc + lane*8 + 4);
    float4 c0 = *(const float4*)(bi + lane*8), c1 = *(const float4*)(bi + lane*8 + 4);
    float scv[8] = {s0.x,s0.y,s0.z,s0.w,s1.x,s1.y,s1.z,s1.w};
    float biv[8] = {c0.x,c0.y,c0.z,c0.w,c1.x,c1.y,c1.z,c1.w};
    float out[8];
    ushort hh[8], ll[8];
    #pragma unroll
    for (int i = 0; i < 8; ++i) {
        out[i] = (x[i] - mean) / den * scv[i] + biv[i];
        hh[i] = bf16_rn(out[i]);
        ll[i] = bf16_rn(out[i] - bf16_f32(hh[i]));
    }
    *(float4*)(h + off)     = (float4){out[0],out[1],out[2],out[3]};
    *(float4*)(h + off + 4) = (float4){out[4],out[5],out[6],out[7]};
    *(ushort4*)(hhi + off)     = (ushort4){hh[0],hh[1],hh[2],hh[3]};
    *(ushort4*)(hhi + off + 4) = (ushort4){hh[4],hh[5],hh[6],hh[7]};
    *(ushort4*)(hlo + off)     = (ushort4){ll[0],ll[1],ll[2],ll[3]};
    *(ushort4*)(hlo + off + 4) = (ushort4){ll[4],ll[5],ll[6],ll[7]};
}

__global__ __launch_bounds__(64)
void sq_kernel(const float* __restrict__ z, float* __restrict__ sq)
{
#pragma clang fp contract(off)
    const int row = blockIdx.x, lane = threadIdx.x;
    const float* p = z + (size_t)row * D_ + (size_t)lane * 8;
    float4 a0 = *(const float4*)(p), a1 = *(const float4*)(p + 4);
    float s = 0.f;
    float vv[8] = {a0.x,a0.y,a0.z,a0.w,a1.x,a1.y,a1.z,a1.w};
    #pragma unroll
    for (int i = 0; i < 8; ++i) { float t = vv[i] * vv[i]; s = s + t; }
    #pragma unroll
    for (int d = 1; d < 64; d <<= 1) s += __shfl_xor(s, d);
    if (lane == 0) sq[row] = s;
}

__global__ __launch_bounds__(256)
void copy_z(const float* __restrict__ z, float* __restrict__ out)
{
    size_t i4 = (size_t)blockIdx.x * 256 + threadIdx.x;
    if (i4 < (size_t)NTOK * D_ / 4) {
        float4 t = ((const float4*)z)[i4];
        out[i4*4+0] = t.x; out[i4*4+1] = t.y;
        out[i4*4+2] = t.z; out[i4*4+3] = t.w;
    }
}

__global__ __launch_bounds__(256)
void gram_kernel(const float* __restrict__ z, float* __restrict__ gram)
{
    __shared__ float Ls[16][68];
    const int s = blockIdx.x;
    const int tid = threadIdx.x;
    const int tx = tid & 15, ty = tid >> 4;
    const int arow = tid >> 2, ak4 = (tid & 3) << 2;
    float acc[4][4] = {};
    const float* zp = z + ((size_t)arow * S_ + s) * D_ + ak4;
    for (int k0 = 0; k0 < D_; k0 += 16) {
        float4 av = *(const float4*)(zp + k0);
        __syncthreads();
        Ls[ak4+0][arow] = av.x; Ls[ak4+1][arow] = av.y;
        Ls[ak4+2][arow] = av.z; Ls[ak4+3][arow] = av.w;
        __syncthreads();
        #pragma unroll
        for (int kk = 0; kk < 16; ++kk) {
            float4 a = *(const float4*)&Ls[kk][ty << 2];
            float4 b = *(const float4*)&Ls[kk][tx << 2];
            float ar[4] = {a.x,a.y,a.z,a.w};
            float br[4] = {b.x,b.y,b.z,b.w};
            #pragma unroll
            for (int i = 0; i < 4; ++i)
                #pragma unroll
                for (int j = 0; j < 4; ++j)
                    acc[i][j] = fmaf(ar[i], br[j], acc[i][j]);
        }
    }
    #pragma unroll
    for (int i = 0; i < 4; ++i) {
        float4 o = {acc[i][0], acc[i][1], acc[i][2], acc[i][3]};
        *(float4*)(gram + ((size_t)s * 64 + (ty<<2) + i) * 64 + (tx<<2)) = o;
    }
}

__global__ __launch_bounds__(64)
void cluster_kernel(const float* __restrict__ gram, const float* __restrict__ sq,
                    const int* __restrict__ y, float* __restrict__ contrib,
                    int* __restrict__ assigned, float* __restrict__ out_assigned_f)
{
#pragma clang fp contract(off)
    __shared__ float G[64][65];
    __shared__ float sqs[64];
    const int s = blockIdx.x, b = threadIdx.x;
    for (int i = b; i < 4096; i += 64)
        G[i >> 6][i & 63] = gram[(size_t)s * 4096 + i];
    sqs[b] = sq[(size_t)b * S_ + s];
    __syncthreads();

    const float sqb = sqs[b];
    float dmin = INFINITY, dsum = 0.f;
    for (int c = 0; c < 64; ++c) {
        float d = sqb + sqs[c] - 2.0f * G[b][c];
        dmin = fminf(dmin, d);
        dsum = dsum + d;
    }
    float Z = 0.f;
    for (int c = 0; c < 64; ++c) {
        float d = sqb + sqs[c] - 2.0f * G[b][c];
        float e = expf(dmin - d);
        G[b][c] = e;
        Z = Z + e;
    }
    for (int c = 0; c < 64; ++c) G[b][c] = G[b][c] / Z;

    int knn[16];
    #pragma unroll
    for (int j = 0; j < 16; ++j) {
        float bp = -1.f; int bi2 = 0;
        for (int c = 0; c < 64; ++c) {
            float pv = G[b][c];
            if (pv > bp) { bp = pv; bi2 = c; }
        }
        knn[j] = bi2;
        G[b][bi2] = -1.f;
    }
    int cmatch = 0;
    #pragma unroll
    for (int j = 0; j < 16; ++j) cmatch += (knn[j] == j) ? 1 : 0;
    int lab[16];
    #pragma unroll
    for (int j = 0; j < 16; ++j) lab[j] = y[knn[j] * S_ + s];
    int bestc = -1, bestcls = 0;
    #pragma unroll
    for (int cls = 0; cls < 16; ++cls) {
        int cc = 0;
        #pragma unroll
        for (int j = 0; j < 16; ++j) cc += (lab[j] == cls) ? 1 : 0;
        if (cc > bestc) { bestc = cc; bestcls = cls; }
    }
    const int oi = s * 64 + b;
    contrib[oi] = dsum * (float)cmatch;
    assigned[oi] = bestcls;
    out_assigned_f[oi] = (float)bestcls;
}

__global__ __launch_bounds__(256)
void finalize_kernel(const float* __restrict__ contrib, const int* __restrict__ assigned,
                     const int* __restrict__ y, float* __restrict__ dout)
{
#pragma clang fp contract(off)
    __shared__ int cm[256];
    __shared__ float red[256];
    const int tid = threadIdx.x;
    cm[tid] = 0;
    float s = 0.f;
    for (int i = tid; i < NTOK; i += 256) s = s + contrib[i];
    red[tid] = s;
    __syncthreads();
    for (int i = tid; i < NTOK; i += 256)
        atomicAdd(&cm[assigned[i] * 16 + y[i]], 1);
    __syncthreads();
    for (int st = 128; st > 0; st >>= 1) {
        if (tid < st) red[tid] = red[tid] + red[tid + st];
        __syncthreads();
    }
    if (tid == 0) {
        dout[0] = red[0];
        float sij = 0.f, sa = 0.f, sb = 0.f;
        for (int i = 0; i < 256; ++i) {
            float mm = (float)cm[i];
            sij = sij + mm * (mm - 1.0f) * 0.5f;
        }
        for (int r = 0; r < 16; ++r) {
            int rs = 0;
            for (int c2 = 0; c2 < 16; ++c2) rs += cm[r * 16 + c2];
            float mm = (float)rs;
            sa = sa + mm * (mm - 1.0f) * 0.5f;
        }
        for (int c2 = 0; c2 < 16; ++c2) {
            int cs = 0;
            for (int r = 0; r < 16; ++r) cs += cm[r * 16 + c2];
            float mm = (float)cs;
            sb = sb + mm * (mm - 1.0f) * 0.5f;
        }
        float n = 16384.0f;
        float expv = sa * sb / (n * (n - 1.0f) * 0.5f);
        float mx = 0.5f * (sa + sb);
        dout[1] = (sij - expv) / (mx - expv);
    }
}

// ---------------------------------------------------------------------------
extern "C" void kernel_launch(void* const* d_in, const int* in_sizes, int n_in,
                              void* d_out, int out_size, void* d_ws, size_t ws_size,
                              hipStream_t stream)
{
    (void)in_sizes; (void)n_in; (void)out_size; (void)ws_size;
    const float* x     = (const float*)d_in[0];
    const float* W_emb = (const float*)d_in[1];
    const float* b_emb = (const float*)d_in[2];
    const float* Wq    = (const float*)d_in[3];
    const float* bq    = (const float*)d_in[4];
    const float* Wk    = (const float*)d_in[5];
    const float* bk    = (const float*)d_in[6];
    const float* Wv    = (const float*)d_in[7];
    const float* bv    = (const float*)d_in[8];
    const float* Wo    = (const float*)d_in[9];
    const float* bo    = (const float*)d_in[10];
    const float* ln1_s = (const float*)d_in[11];
    const float* ln1_b = (const float*)d_in[12];
    const float* W1    = (const float*)d_in[13];
    const float* b1    = (const float*)d_in[14];
    const float* W2    = (const float*)d_in[15];
    const float* b2    = (const float*)d_in[16];
    const float* ln2_s = (const float*)d_in[17];
    const float* ln2_b = (const float*)d_in[18];
    const float* e1_w  = (const float*)d_in[19];
    const float* e1_b  = (const float*)d_in[20];
    const float* e2_w  = (const float*)d_in[21];
    const float* e2_b  = (const float*)d_in[22];
    const float* d1_w  = (const float*)d_in[23];
    const float* d1_b  = (const float*)d_in[24];
    const float* d2_w  = (const float*)d_in[25];
    const float* d2_b  = (const float*)d_in[26];
    const int*   y     = (const int*)d_in[27];

    float* ws = (float*)d_ws;
    float*  h    = ws;                                   // 8388608
    ushort* hhi  = (ushort*)(ws + 8388608);
    ushort* hlo  = (ushort*)(ws + 12582912);
    float*  SCR  = ws + 16777216;                        // 20971520 slots scratch
    ushort* obhi = (ushort*)(ws + 37748736);
    ushort* oblo = (ushort*)(ws + 41943040);
    float*  wt   = ws + 46137344;
    ushort* WTQKV_HI = (ushort*)wt;
    ushort* WTQKV_LO = WTQKV_HI + 786432;
    ushort* WTO_HI   = WTQKV_LO + 786432;
    ushort* WTO_LO   = WTO_HI + 262144;
    ushort* WT1_HI   = WTO_LO + 262144;
    ushort* WT1_LO   = WT1_HI + 1048576;
    ushort* WT2_HI   = WT1_LO + 1048576;
    ushort* WT2_LO   = WT2_HI + 1048576;
    ushort* WE1_HI   = WT2_LO + 1048576;
    ushort* WE1_LO   = WE1_HI + 65536;
    ushort* WE2_HI   = WE1_LO + 65536;
    ushort* WE2_LO   = WE2_HI + 65536;
    ushort* WD1_HI   = WE2_LO + 65536;
    ushort* WD1_LO   = WD1_HI + 65536;
    ushort* WD2_HI   = WD1_LO + 65536;
    ushort* WD2_LO   = WD2_HI + 65536;
    float*  biasqkv  = ws + 49545216;

    float*  Sb    = SCR;
    ushort* qkvhi = (ushort*)(SCR + 8388608);
    ushort* qkvlo = (ushort*)(SCR + 11534336);
    ushort* VThi  = (ushort*)(SCR + 14680064);
    ushort* VTlo  = (ushort*)(SCR + 15728640);
    ushort* Phi_  = (ushort*)(SCR + 8388608);
    ushort* Plo_  = (ushort*)(SCR + 16777216);
    float*  Of32  = SCR;
    ushort* f1hi  = (ushort*)SCR;
    ushort* f1lo  = (ushort*)(SCR + 8388608);
    float*  Xhalf = SCR + 16777216;
    ushort* enchi = (ushort*)SCR;
    ushort* enclo = (ushort*)(SCR + 4194304);
    float*  z     = SCR + 8388608;
    float*  gram  = SCR + 16777216;
    float*  sqb_  = SCR + 17825792;
    float*  contrib = SCR + 17842176;
    int*    assigned = (int*)(SCR + 17858560);
    ushort* t1hi = obhi;
    ushort* t1lo = oblo;
    ushort* t2hi = obhi + 2097152;
    ushort* t2lo = oblo + 2097152;
    float*  dout = (float*)d_out;

    dim3 blk(256);
    auto gg = [](int M, int N) { return dim3(N >> 7, M >> 7); };

    transpose_split<<<dim3(2, 8), blk, 0, stream>>>(e1_w, WE1_HI, WE1_LO, 512, 128);
    transpose_split<<<dim3(8, 2), blk, 0, stream>>>(e2_w, WE2_HI, WE2_LO, 128, 512);
    transpose_split<<<dim3(2, 8), blk, 0, stream>>>(d1_w, WD1_HI, WD1_LO, 512, 128);
    transpose_split<<<dim3(8, 2), blk, 0, stream>>>(d2_w, WD2_HI, WD2_LO, 128, 512);

    gemm_f32<<<dim3(8, 256), blk, 0, stream>>>(x, W_emb, b_emb, h, hhi, hlo, NTOK, D_, IN_);

    for (int l = 0; l < L_; ++l) {
        transpose_split<<<dim3(8, 8), blk, 0, stream>>>(Wq + (size_t)l*D_*D_, WTQKV_HI,            WTQKV_LO,            512, 512);
        transpose_split<<<dim3(8, 8), blk, 0, stream>>>(Wk + (size_t)l*D_*D_, WTQKV_HI + 512*512,  WTQKV_LO + 512*512,  512, 512);
        transpose_split<<<dim3(8, 8), blk, 0, stream>>>(Wv + (size_t)l*D_*D_, WTQKV_HI + 1024*512, WTQKV_LO + 1024*512, 512, 512);
        transpose_split<<<dim3(8, 8), blk, 0, stream>>>(Wo + (size_t)l*D_*D_, WTO_HI, WTO_LO, 512, 512);
        transpose_split<<<dim3(32, 8), blk, 0, stream>>>(W1 + (size_t)l*D_*DFF_, WT1_HI, WT1_LO, 512, 2048);
        transpose_split<<<dim3(8, 32), blk, 0, stream>>>(W2 + (size_t)l*DFF_*D_, WT2_HI, WT2_LO, 2048, 512);
        concat3<<<dim3(6), blk, 0, stream>>>(bq + l*D_, bk + l*D_, bv + l*D_, biasqkv);

        for (int qtr = 0; qtr < 4; ++qtr) {
            const size_t hoff = (size_t)qtr * 4096 * 512;
            gemm3<2><<<gg(4096, 1536), blk, 0, stream>>>(
                hhi + hoff, hlo + hoff, WTQKV_HI, WTQKV_LO, biasqkv,
                nullptr, qkvhi, qkvlo, 4096, 1536, 512);
            vtrans<<<dim3(128), blk, 0, stream>>>(qkvhi, qkvlo, VThi, VTlo);
            qk_gemm<<<dim3(4, 128), blk, 0, stream>>>(qkvhi, qkvlo, Sb);
            softmax_p<<<dim3(8192), blk, 0, stream>>>(Sb, Phi_, Plo_);
            pv_gemm<<<dim3(2, 128), blk, 0, stream>>>(Phi_, Plo_, VThi, VTlo,
                                                      obhi, oblo, qtr * 4096);
        }
        gemm3<0><<<gg(NTOK, 512), blk, 0, stream>>>(
            obhi, oblo, WTO_HI, WTO_LO, bo + l*D_,
            Of32, nullptr, nullptr, NTOK, 512, 512);
        ln_res<<<dim3(NTOK), dim3(64), 0, stream>>>(h, Of32, ln1_s + l*D_, ln1_b + l*D_, hhi, hlo);

        for (int half = 0; half < 2; ++half) {
            const size_t ro = (size_t)half * HALF_ * D_;
            // FFN1: 8-phase 256^2 kernel (grid 8x32 = 256 blocks = 1/CU)
            gemm3_8p<3><<<dim3(DFF_ >> 8, HALF_ >> 8), dim3(512), 0, stream>>>(
                hhi + ro, hlo + ro, WT1_HI, WT1_LO, b1 + l*DFF_,
                nullptr, f1hi, f1lo, HALF_, 2048, 512);
            gemm3<0><<<gg(HALF_, 512), blk, 0, stream>>>(
                f1hi, f1lo, WT2_HI, WT2_LO, b2 + l*D_,
                Xhalf, nullptr, nullptr, HALF_, 512, 2048);
            ln_res<<<dim3(HALF_), dim3(64), 0, stream>>>(
                h + ro, Xhalf, ln2_s + l*D_, ln2_b + l*D_, hhi + ro, hlo + ro);
        }
    }

    gemm3<3><<<gg(NTOK, 128), blk, 0, stream>>>(
        hhi, hlo, WE1_HI, WE1_LO, e1_b, nullptr, t1hi, t1lo, NTOK, 128, 512);
    gemm3<2><<<gg(NTOK, 512), blk, 0, stream>>>(
        t1hi, t1lo, WE2_HI, WE2_LO, e2_b, nullptr, enchi, enclo, NTOK, 512, 128);
    gemm3<3><<<gg(NTOK, 128), blk, 0, stream>>>(
        enchi, enclo, WD1_HI, WD1_LO, d1_b, nullptr, t2hi, t2lo, NTOK, 128, 512);
    gemm3<0><<<gg(NTOK, 512), blk, 0, stream>>>(
        t2hi, t2lo, WD2_HI, WD2_LO, d2_b, z, nullptr, nullptr, NTOK, 512, 128);

    copy_z<<<dim3(NTOK * D_ / 4 / 256), blk, 0, stream>>>(z, dout + 16386);
    sq_kernel<<<dim3(NTOK), dim3(64), 0, stream>>>(z, sqb_);
    gram_kernel<<<dim3(S_), blk, 0, stream>>>(z, gram);
    cluster_kernel<<<dim3(S_), dim3(64), 0, stream>>>(gram, sqb_, y, contrib, assigned, dout + 2);
    finalize_kernel<<<dim3(1), blk, 0, stream>>>(contrib, assigned, y, dout);
}

// Round 9
// 1499.546 us; speedup vs baseline: 1.1178x; 1.1178x over previous
//
#include <hip/hip_runtime.h>
#include <cstdint>
#include <cmath>

#define B_ 64
#define S_ 256
#define IN_ 32
#define D_ 512
#define H_ 8
#define L_ 2
#define DFF_ 2048
#define C_ 16
#define DH_ 64
#define NTOK (B_*S_)   // 16384
#define HALF_ 8192

typedef __attribute__((ext_vector_type(8))) short bf16x8;
typedef __attribute__((ext_vector_type(4))) float f32x4;
typedef __attribute__((ext_vector_type(8))) ushort ushortx8;

__device__ __forceinline__ ushort bf16_rn(float x) {
    union { float f; uint32_t u; } v; v.f = x;
    uint32_t r = v.u + 0x7fffu + ((v.u >> 16) & 1u);
    return (ushort)(r >> 16);
}
__device__ __forceinline__ float bf16_f32(ushort h) {
    union { uint32_t u; float f; } v; v.u = ((uint32_t)h) << 16;
    return v.f;
}

#define GLDS(gp, lp) __builtin_amdgcn_global_load_lds( \
    (const __attribute__((address_space(1))) void*)(gp), \
    (__attribute__((address_space(3))) void*)(lp), 16, 0, 0)

// XCD-chunk bijective swizzle (nwg % 8 == 0 for all users).
__device__ __forceinline__ int xcd_swz(int lid, int nwg) {
    return (lid & 7) * (nwg >> 3) + (lid >> 3);
}

// ---------------------------------------------------------------------------
// Merged bf16x3 GEMM (128x128, 2-phase, counted vmcnt). All 4 operand streams
// staged once per K-tile (48 MFMA : 16 ds_read_b128), 64 KB LDS dbuf.
// MODE: 0 = f32 out, 2 = split hi/lo out, 3 = split + ReLU.
// ---------------------------------------------------------------------------
template<int MODE>
__global__ __launch_bounds__(256)
void gemm3(const ushort* __restrict__ Ahi, const ushort* __restrict__ Alo,
           const ushort* __restrict__ Bhi, const ushort* __restrict__ Blo,
           const float* __restrict__ bias,
           float* __restrict__ Cf, ushort* __restrict__ Chi, ushort* __restrict__ Clo,
           int M, int N, int K)
{
    __shared__ __align__(16) ushort Als[2][2][128*32];
    __shared__ __align__(16) ushort Bls[2][2][128*32];
    const int tid  = threadIdx.x;
    const int wave = tid >> 6, lane = tid & 63;
    const int nwg = gridDim.x * gridDim.y;
    const int swz = xcd_swz(blockIdx.y * gridDim.x + blockIdx.x, nwg);
    const int m0 = (swz / gridDim.x) << 7, n0 = (swz % gridDim.x) << 7;
    const int wr = wave >> 1, wc = wave & 1;

    const ushort* Ah = Ahi + (size_t)m0 * K;
    const ushort* Al = Alo + (size_t)m0 * K;
    const ushort* Bh = Bhi + (size_t)n0 * K;
    const ushort* Bl = Blo + (size_t)n0 * K;

    const int KT = K >> 5;

    f32x4 acc[4][4];
    #pragma unroll
    for (int m = 0; m < 4; ++m)
        #pragma unroll
        for (int n = 0; n < 4; ++n)
            acc[m][n] = (f32x4){0.f, 0.f, 0.f, 0.f};

    auto stage = [&](int buf, int kk) {
        #pragma unroll
        for (int i = 0; i < 2; ++i) {
            const int rbase = wave * 32 + i * 16;
            const int row   = rbase + (lane >> 2);
            const int slot  = (lane & 3) ^ ((row >> 1) & 3);
            GLDS(Ah + (size_t)row * K + kk + slot * 8, &Als[buf][0][rbase * 32]);
            GLDS(Al + (size_t)row * K + kk + slot * 8, &Als[buf][1][rbase * 32]);
            GLDS(Bh + (size_t)row * K + kk + slot * 8, &Bls[buf][0][rbase * 32]);
            GLDS(Bl + (size_t)row * K + kk + slot * 8, &Bls[buf][1][rbase * 32]);
        }
    };

    stage(0, 0);
    for (int t = 0; t < KT; ++t) {
        const int buf = t & 1;
        if (t + 1 < KT) {
            stage(buf ^ 1, (t + 1) << 5);
            asm volatile("s_waitcnt vmcnt(8)" ::: "memory");
        } else {
            asm volatile("s_waitcnt vmcnt(0)" ::: "memory");
        }
        __builtin_amdgcn_sched_barrier(0);
        __builtin_amdgcn_s_barrier();

        const int chunk = lane >> 4;
        bf16x8 afh[4], afl[4], bfh[4], bfl[4];
        #pragma unroll
        for (int m = 0; m < 4; ++m) {
            const int row = wr * 64 + m * 16 + (lane & 15);
            const int sl  = chunk ^ ((row >> 1) & 3);
            afh[m] = *(const bf16x8*)(&Als[buf][0][row * 32 + sl * 8]);
            afl[m] = *(const bf16x8*)(&Als[buf][1][row * 32 + sl * 8]);
        }
        #pragma unroll
        for (int n = 0; n < 4; ++n) {
            const int row = wc * 64 + n * 16 + (lane & 15);
            const int sl  = chunk ^ ((row >> 1) & 3);
            bfh[n] = *(const bf16x8*)(&Bls[buf][0][row * 32 + sl * 8]);
            bfl[n] = *(const bf16x8*)(&Bls[buf][1][row * 32 + sl * 8]);
        }
        #pragma unroll
        for (int m = 0; m < 4; ++m)
            #pragma unroll
            for (int n = 0; n < 4; ++n) {
                acc[m][n] = __builtin_amdgcn_mfma_f32_16x16x32_bf16(afh[m], bfh[n], acc[m][n], 0, 0, 0);
                acc[m][n] = __builtin_amdgcn_mfma_f32_16x16x32_bf16(afh[m], bfl[n], acc[m][n], 0, 0, 0);
                acc[m][n] = __builtin_amdgcn_mfma_f32_16x16x32_bf16(afl[m], bfh[n], acc[m][n], 0, 0, 0);
            }
        __builtin_amdgcn_sched_barrier(0);
        __builtin_amdgcn_s_barrier();
    }

    const int col_l = lane & 15;
    float bv[4];
    #pragma unroll
    for (int n = 0; n < 4; ++n) bv[n] = bias[n0 + wc * 64 + n * 16 + col_l];
    #pragma unroll
    for (int m = 0; m < 4; ++m) {
        #pragma unroll
        for (int j = 0; j < 4; ++j) {
            const size_t grow = (size_t)(m0 + wr * 64 + m * 16 + (lane >> 4) * 4 + j);
            #pragma unroll
            for (int n = 0; n < 4; ++n) {
                float x = acc[m][n][j] + bv[n];
                if (MODE & 1) x = fmaxf(x, 0.f);
                const size_t gidx = grow * N + (n0 + wc * 64 + n * 16 + col_l);
                if (MODE < 2) {
                    Cf[gidx] = x;
                } else {
                    ushort hb = bf16_rn(x);
                    Chi[gidx] = hb;
                    Clo[gidx] = bf16_rn(x - bf16_f32(hb));
                }
            }
        }
    }
}

// ---------------------------------------------------------------------------
// Fused QK^T + row-softmax (bf16x3): block computes a full 128q x 256k score
// tile for one (bh, qt); wave owns 32q x 256k so each row lives in one wave.
// Q(hi/lo) + one K-half(hi/lo) staged in 64 KB LDS (2 blocks/CU); K staged in
// two 128-row halves, barrier-separated. Row softmax in-register (per-lane
// 16-value reduce + shfl_xor over the 16-lane group). P written split hi/lo.
// grid = (2 [qt], 128 [bh]).
// ---------------------------------------------------------------------------
__global__ __launch_bounds__(256)
void qks_gemm(const ushort* __restrict__ qkvhi, const ushort* __restrict__ qkvlo,
              ushort* __restrict__ Phi, ushort* __restrict__ Plo)
{
    __shared__ __align__(16) ushort Qls[2][128*64];   // [hi/lo][row*64]
    __shared__ __align__(16) ushort Kls[2][128*64];
    const int tid = threadIdx.x, wave = tid >> 6, lane = tid & 63;
    const int swz = xcd_swz(blockIdx.y * 2 + blockIdx.x, 256);
    const int bh = swz >> 1, qt = swz & 1;
    const int b = bh >> 3, h = bh & 7;

    const ushort* Qh = qkvhi + ((size_t)(b * 256 + qt * 128)) * 1536 + h * 64;
    const ushort* Ql = qkvlo + ((size_t)(b * 256 + qt * 128)) * 1536 + h * 64;
    const ushort* Kh = qkvhi + ((size_t)(b * 256)) * 1536 + 512 + h * 64;
    const ushort* Kl = qkvlo + ((size_t)(b * 256)) * 1536 + 512 + h * 64;

    // stage 128 rows (stride 1536) into a [128*64] LDS array; source
    // pre-swizzled slot^(row&7), LDS linear (rule 21 both-sides pattern).
    auto stage128 = [&](const ushort* src, ushort* dst) {
        #pragma unroll
        for (int j = 0; j < 4; ++j) {
            const int rl   = j * 32 + wave * 8 + (lane >> 3);
            const int slot = (lane & 7) ^ (rl & 7);
            GLDS(src + (size_t)rl * 1536 + slot * 8, dst + (j * 32 + wave * 8) * 64);
        }
    };

    f32x4 acc[2][16];
    #pragma unroll
    for (int mi = 0; mi < 2; ++mi)
        #pragma unroll
        for (int nj = 0; nj < 16; ++nj)
            acc[mi][nj] = (f32x4){0.f, 0.f, 0.f, 0.f};

    stage128(Qh, &Qls[0][0]);
    stage128(Ql, &Qls[1][0]);
    stage128(Kh, &Kls[0][0]);
    stage128(Kl, &Kls[1][0]);
    asm volatile("s_waitcnt vmcnt(0)" ::: "memory");
    __builtin_amdgcn_sched_barrier(0);
    __builtin_amdgcn_s_barrier();

    // Q fragments held for the whole kernel
    bf16x8 qh[2][2], ql[2][2];
    #pragma unroll
    for (int mi = 0; mi < 2; ++mi)
        #pragma unroll
        for (int ks = 0; ks < 2; ++ks) {
            const int row = wave * 32 + mi * 16 + (lane & 15);
            const int es  = (ks * 4 + (lane >> 4)) ^ (lane & 7);
            qh[mi][ks] = *(const bf16x8*)&Qls[0][row * 64 + es * 8];
            ql[mi][ks] = *(const bf16x8*)&Qls[1][row * 64 + es * 8];
        }

    #pragma unroll
    for (int hk = 0; hk < 2; ++hk) {
        if (hk == 1) {
            __syncthreads();                       // all reads of K-half0 done
            stage128(Kh + (size_t)128 * 1536, &Kls[0][0]);
            stage128(Kl + (size_t)128 * 1536, &Kls[1][0]);
            asm volatile("s_waitcnt vmcnt(0)" ::: "memory");
            __builtin_amdgcn_sched_barrier(0);
            __builtin_amdgcn_s_barrier();
        }
        #pragma unroll
        for (int ng = 0; ng < 2; ++ng) {
            bf16x8 kh[4][2], kl[4][2];
            #pragma unroll
            for (int nj = 0; nj < 4; ++nj)
                #pragma unroll
                for (int ks = 0; ks < 2; ++ks) {
                    const int row = (ng * 4 + nj) * 16 + (lane & 15);
                    const int es  = (ks * 4 + (lane >> 4)) ^ (lane & 7);
                    kh[nj][ks] = *(const bf16x8*)&Kls[0][row * 64 + es * 8];
                    kl[nj][ks] = *(const bf16x8*)&Kls[1][row * 64 + es * 8];
                }
            #pragma unroll
            for (int mi = 0; mi < 2; ++mi)
                #pragma unroll
                for (int nj = 0; nj < 4; ++nj) {
                    const int an = hk * 8 + ng * 4 + nj;
                    #pragma unroll
                    for (int ks = 0; ks < 2; ++ks) {
                        acc[mi][an] = __builtin_amdgcn_mfma_f32_16x16x32_bf16(qh[mi][ks], kh[nj][ks], acc[mi][an], 0, 0, 0);
                        acc[mi][an] = __builtin_amdgcn_mfma_f32_16x16x32_bf16(qh[mi][ks], kl[nj][ks], acc[mi][an], 0, 0, 0);
                        acc[mi][an] = __builtin_amdgcn_mfma_f32_16x16x32_bf16(ql[mi][ks], kh[nj][ks], acc[mi][an], 0, 0, 0);
                    }
                }
        }
    }

    // row softmax + split-bf16 P write
    const int colb = lane & 15;
    #pragma unroll
    for (int mi = 0; mi < 2; ++mi) {
        #pragma unroll
        for (int j = 0; j < 4; ++j) {
            float v[16];
            float mx = -INFINITY;
            #pragma unroll
            for (int nj = 0; nj < 16; ++nj) {
                v[nj] = acc[mi][nj][j] * 0.125f;
                mx = fmaxf(mx, v[nj]);
            }
            #pragma unroll
            for (int d = 1; d < 16; d <<= 1) mx = fmaxf(mx, __shfl_xor(mx, d));
            float sum = 0.f;
            #pragma unroll
            for (int nj = 0; nj < 16; ++nj) {
                v[nj] = expf(v[nj] - mx);
                sum += v[nj];
            }
            #pragma unroll
            for (int d = 1; d < 16; d <<= 1) sum += __shfl_xor(sum, d);
            const float inv = 1.0f / sum;
            const int qrow = qt * 128 + wave * 32 + mi * 16 + (lane >> 4) * 4 + j;
            const size_t base = ((size_t)bh * 256 + qrow) * 256;
            #pragma unroll
            for (int nj = 0; nj < 16; ++nj) {
                float p = v[nj] * inv;
                ushort hb = bf16_rn(p);
                Phi[base + nj * 16 + colb] = hb;
                Plo[base + nj * 16 + colb] = bf16_rn(p - bf16_f32(hb));
            }
        }
    }
}

// ---------------------------------------------------------------------------
// V transpose per (bh): VT[dh][key] = V[key][dh], hi and lo passes.
// ---------------------------------------------------------------------------
__global__ __launch_bounds__(256)
void vtrans(const ushort* __restrict__ qkvhi, const ushort* __restrict__ qkvlo,
            ushort* __restrict__ VThi, ushort* __restrict__ VTlo)
{
    __shared__ ushort T[64][272];
    const int bh = blockIdx.x;
    const int b = bh >> 3, h = bh & 7;
    const int tid = threadIdx.x;
    #pragma unroll
    for (int pass = 0; pass < 2; ++pass) {
        const ushort* src = pass ? qkvlo : qkvhi;
        ushort* dst = pass ? VTlo : VThi;
        const ushort* p = src + ((size_t)b * 256 + tid) * 1536 + 1024 + h * 64;
        #pragma unroll
        for (int i = 0; i < 8; ++i) {
            ushortx8 v = *(const ushortx8*)(p + i * 8);
            #pragma unroll
            for (int j = 0; j < 8; ++j) T[i * 8 + j][tid] = v[j];
        }
        __syncthreads();
        const int dh = tid >> 2, k0 = (tid & 3) * 64;
        ushort* op = dst + ((size_t)bh * 64 + dh) * 256 + k0;
        #pragma unroll
        for (int i = 0; i < 8; ++i)
            *(ushortx8*)(op + i * 8) = *(const ushortx8*)&T[dh][k0 + i * 8];
        __syncthreads();
    }
}

// ---------------------------------------------------------------------------
// Batched PV: O[q][dh] = P[q][:] . V[:, dh] (bf16x3), O written split hi/lo.
// grid = (2 [qt], 128 [bh]). Tile 128x64.
// ---------------------------------------------------------------------------
__global__ __launch_bounds__(256)
void pv_gemm(const ushort* __restrict__ Phi, const ushort* __restrict__ Plo,
             const ushort* __restrict__ VThi, const ushort* __restrict__ VTlo,
             ushort* __restrict__ obhi, ushort* __restrict__ oblo, int t0)
{
    __shared__ __align__(16) ushort Als[2][2][128*32];
    __shared__ __align__(16) ushort Bls[2][2][64*32];
    const int tid = threadIdx.x, wave = tid >> 6, lane = tid & 63;
    const int swz = xcd_swz(blockIdx.y * 2 + blockIdx.x, 256);
    const int bh = swz >> 1, qt = swz & 1;
    const ushort* Ah = Phi + ((size_t)bh * 256 + qt * 128) * 256;
    const ushort* Al = Plo + ((size_t)bh * 256 + qt * 128) * 256;
    const ushort* Bh = VThi + (size_t)bh * 64 * 256;
    const ushort* Bl = VTlo + (size_t)bh * 64 * 256;

    f32x4 acc[2][4];
    #pragma unroll
    for (int m = 0; m < 2; ++m)
        #pragma unroll
        for (int n = 0; n < 4; ++n)
            acc[m][n] = (f32x4){0.f, 0.f, 0.f, 0.f};

    auto stage = [&](int buf, int kk) {
        #pragma unroll
        for (int i = 0; i < 2; ++i) {
            const int rbase = wave * 32 + i * 16;
            const int row   = rbase + (lane >> 2);
            const int slot  = (lane & 3) ^ ((row >> 1) & 3);
            GLDS(Ah + (size_t)row * 256 + kk + slot * 8, &Als[buf][0][rbase * 32]);
            GLDS(Al + (size_t)row * 256 + kk + slot * 8, &Als[buf][1][rbase * 32]);
        }
        const int rbase2 = wave * 16;
        const int row2   = rbase2 + (lane >> 2);
        const int slot2  = (lane & 3) ^ ((row2 >> 1) & 3);
        GLDS(Bh + (size_t)row2 * 256 + kk + slot2 * 8, &Bls[buf][0][rbase2 * 32]);
        GLDS(Bl + (size_t)row2 * 256 + kk + slot2 * 8, &Bls[buf][1][rbase2 * 32]);
    };

    stage(0, 0);
    for (int t = 0; t < 8; ++t) {
        const int buf = t & 1;
        __syncthreads();
        if (t < 7) stage(buf ^ 1, (t + 1) << 5);
        const int chunk = lane >> 4;
        bf16x8 afh[2], afl[2], bfh[4], bfl[4];
        #pragma unroll
        for (int m = 0; m < 2; ++m) {
            const int row = wave * 32 + m * 16 + (lane & 15);
            const int sl  = chunk ^ ((row >> 1) & 3);
            afh[m] = *(const bf16x8*)(&Als[buf][0][row * 32 + sl * 8]);
            afl[m] = *(const bf16x8*)(&Als[buf][1][row * 32 + sl * 8]);
        }
        #pragma unroll
        for (int n = 0; n < 4; ++n) {
            const int row = n * 16 + (lane & 15);
            const int sl  = chunk ^ ((row >> 1) & 3);
            bfh[n] = *(const bf16x8*)(&Bls[buf][0][row * 32 + sl * 8]);
            bfl[n] = *(const bf16x8*)(&Bls[buf][1][row * 32 + sl * 8]);
        }
        #pragma unroll
        for (int m = 0; m < 2; ++m)
            #pragma unroll
            for (int n = 0; n < 4; ++n) {
                acc[m][n] = __builtin_amdgcn_mfma_f32_16x16x32_bf16(afh[m], bfh[n], acc[m][n], 0, 0, 0);
                acc[m][n] = __builtin_amdgcn_mfma_f32_16x16x32_bf16(afh[m], bfl[n], acc[m][n], 0, 0, 0);
                acc[m][n] = __builtin_amdgcn_mfma_f32_16x16x32_bf16(afl[m], bfh[n], acc[m][n], 0, 0, 0);
            }
        __syncthreads();
    }

    const int b = bh >> 3, h = bh & 7;
    const int col_l = lane & 15;
    #pragma unroll
    for (int m = 0; m < 2; ++m)
        #pragma unroll
        for (int j = 0; j < 4; ++j) {
            const int q = qt * 128 + wave * 32 + m * 16 + (lane >> 4) * 4 + j;
            const size_t token = (size_t)t0 + (size_t)b * 256 + q;
            #pragma unroll
            for (int n = 0; n < 4; ++n) {
                const int col = h * 64 + n * 16 + col_l;
                float x = acc[m][n][j];
                ushort hb = bf16_rn(x);
                obhi[token * 512 + col] = hb;
                oblo[token * 512 + col] = bf16_rn(x - bf16_f32(hb));
            }
        }
}

// ---------------------------------------------------------------------------
// f32 GEMM (embedding only, K=32) with fused bf16 hi/lo split output.
// ---------------------------------------------------------------------------
__global__ __launch_bounds__(256)
void gemm_f32(const float* __restrict__ A, const float* __restrict__ W,
              const float* __restrict__ bias, float* __restrict__ Cc,
              ushort* __restrict__ Chi, ushort* __restrict__ Clo,
              int M, int N, int K)
{
    __shared__ float As[16][68];
    __shared__ float Bs[16][64];
    const int tid = threadIdx.x;
    const int tx = tid & 15, ty = tid >> 4;
    const int m0 = blockIdx.y << 6, n0 = blockIdx.x << 6;
    const int arow = tid >> 2, ak4 = (tid & 3) << 2;
    const int brow = tid >> 4, bc4 = (tid & 15) << 2;
    float acc[4][4] = {};
    const float* aptr = A + (size_t)(m0 + arow) * K + ak4;
    const float* bptr = W + (size_t)brow * N + n0 + bc4;
    for (int k0 = 0; k0 < K; k0 += 16) {
        float4 av = *(const float4*)(aptr + k0);
        float4 bv = *(const float4*)(bptr + (size_t)k0 * N);
        __syncthreads();
        As[ak4+0][arow] = av.x; As[ak4+1][arow] = av.y;
        As[ak4+2][arow] = av.z; As[ak4+3][arow] = av.w;
        *(float4*)&Bs[brow][bc4] = bv;
        __syncthreads();
        #pragma unroll
        for (int kk = 0; kk < 16; ++kk) {
            float4 a = *(const float4*)&As[kk][ty << 2];
            float4 b = *(const float4*)&Bs[kk][tx << 2];
            float ar[4] = {a.x,a.y,a.z,a.w};
            float br[4] = {b.x,b.y,b.z,b.w};
            #pragma unroll
            for (int i = 0; i < 4; ++i)
                #pragma unroll
                for (int j = 0; j < 4; ++j)
                    acc[i][j] = fmaf(ar[i], br[j], acc[i][j]);
        }
    }
    float4 bb = *(const float4*)(bias + n0 + (tx << 2));
    #pragma unroll
    for (int i = 0; i < 4; ++i) {
        int m = m0 + (ty << 2) + i;
        float o[4];
        o[0] = acc[i][0] + bb.x; o[1] = acc[i][1] + bb.y;
        o[2] = acc[i][2] + bb.z; o[3] = acc[i][3] + bb.w;
        ushort4 hh, ll;
        hh.x = bf16_rn(o[0]); ll.x = bf16_rn(o[0] - bf16_f32(hh.x));
        hh.y = bf16_rn(o[1]); ll.y = bf16_rn(o[1] - bf16_f32(hh.y));
        hh.z = bf16_rn(o[2]); ll.z = bf16_rn(o[2] - bf16_f32(hh.z));
        hh.w = bf16_rn(o[3]); ll.w = bf16_rn(o[3] - bf16_f32(hh.w));
        const size_t base = (size_t)m * N + n0 + (tx << 2);
        *(float4*)(Cc + base) = (float4){o[0],o[1],o[2],o[3]};
        *(ushort4*)(Chi + base) = hh;
        *(ushort4*)(Clo + base) = ll;
    }
}

__global__ __launch_bounds__(256)
void transpose_split(const float* __restrict__ W, ushort* __restrict__ Thi,
                     ushort* __restrict__ Tlo, int K, int N)
{
    __shared__ float T[64][65];
    const int k0 = blockIdx.y << 6, n0 = blockIdx.x << 6;
    const int tid = threadIdx.x;
    #pragma unroll
    for (int i = 0; i < 16; ++i) {
        int idx = tid + i * 256;
        int kl = idx >> 6, nl = idx & 63;
        T[nl][kl] = W[(size_t)(k0 + kl) * N + n0 + nl];
    }
    __syncthreads();
    #pragma unroll
    for (int i = 0; i < 16; ++i) {
        int idx = tid + i * 256;
        int nl = idx >> 6, kl = idx & 63;
        float x = T[nl][kl];
        ushort hb = bf16_rn(x);
        size_t o = (size_t)(n0 + nl) * K + k0 + kl;
        Thi[o] = hb;
        Tlo[o] = bf16_rn(x - bf16_f32(hb));
    }
}

__global__ __launch_bounds__(256)
void concat3(const float* __restrict__ a, const float* __restrict__ b,
             const float* __restrict__ c, float* __restrict__ out)
{
    int i = blockIdx.x * 256 + threadIdx.x;
    out[i] = (i < 512) ? a[i] : (i < 1024 ? b[i - 512] : c[i - 1024]);
}

// ---------------------------------------------------------------------------
// residual + LN: 4 rows per 256-thread block (one wave per row).
// ---------------------------------------------------------------------------
__global__ __launch_bounds__(256)
void ln_res(float* __restrict__ h, const float* __restrict__ t,
            const float* __restrict__ sc, const float* __restrict__ bi,
            ushort* __restrict__ hhi, ushort* __restrict__ hlo)
{
    const int row = blockIdx.x * 4 + (threadIdx.x >> 6);
    const int lane = threadIdx.x & 63;
    const size_t off = (size_t)row * D_ + (size_t)lane * 8;
    float x[8];
    float4 a0 = *(const float4*)(h + off),  a1 = *(const float4*)(h + off + 4);
    float4 b0 = *(const float4*)(t + off),  b1 = *(const float4*)(t + off + 4);
    x[0]=a0.x+b0.x; x[1]=a0.y+b0.y; x[2]=a0.z+b0.z; x[3]=a0.w+b0.w;
    x[4]=a1.x+b1.x; x[5]=a1.y+b1.y; x[6]=a1.z+b1.z; x[7]=a1.w+b1.w;

    float s = 0.f;
    #pragma unroll
    for (int i = 0; i < 8; ++i) s += x[i];
    #pragma unroll
    for (int d = 1; d < 64; d <<= 1) s += __shfl_xor(s, d);
    float mean = s * (1.0f / 512.0f);

    float vsum = 0.f;
    #pragma unroll
    for (int i = 0; i < 8; ++i) { float dx = x[i] - mean; vsum += dx * dx; }
    #pragma unroll
    for (int d = 1; d < 64; d <<= 1) vsum += __shfl_xor(vsum, d);
    float den = sqrtf(vsum * (1.0f / 512.0f) + 1e-5f);

    float4 s0 = *(const float4*)(sc + lane*8), s1 = *(const float4*)(sc + lane*8 + 4);
    float4 c0 = *(const float4*)(bi + lane*8), c1 = *(const float4*)(bi + lane*8 + 4);
    float scv[8] = {s0.x,s0.y,s0.z,s0.w,s1.x,s1.y,s1.z,s1.w};
    float biv[8] = {c0.x,c0.y,c0.z,c0.w,c1.x,c1.y,c1.z,c1.w};
    float out[8];
    ushort hh[8], ll[8];
    #pragma unroll
    for (int i = 0; i < 8; ++i) {
        out[i] = (x[i] - mean) / den * scv[i] + biv[i];
        hh[i] = bf16_rn(out[i]);
        ll[i] = bf16_rn(out[i] - bf16_f32(hh[i]));
    }
    *(float4*)(h + off)     = (float4){out[0],out[1],out[2],out[3]};
    *(float4*)(h + off + 4) = (float4){out[4],out[5],out[6],out[7]};
    *(ushort4*)(hhi + off)     = (ushort4){hh[0],hh[1],hh[2],hh[3]};
    *(ushort4*)(hhi + off + 4) = (ushort4){hh[4],hh[5],hh[6],hh[7]};
    *(ushort4*)(hlo + off)     = (ushort4){ll[0],ll[1],ll[2],ll[3]};
    *(ushort4*)(hlo + off + 4) = (ushort4){ll[4],ll[5],ll[6],ll[7]};
}

__global__ __launch_bounds__(64)
void sq_kernel(const float* __restrict__ z, float* __restrict__ sq)
{
#pragma clang fp contract(off)
    const int row = blockIdx.x, lane = threadIdx.x;
    const float* p = z + (size_t)row * D_ + (size_t)lane * 8;
    float4 a0 = *(const float4*)(p), a1 = *(const float4*)(p + 4);
    float s = 0.f;
    float vv[8] = {a0.x,a0.y,a0.z,a0.w,a1.x,a1.y,a1.z,a1.w};
    #pragma unroll
    for (int i = 0; i < 8; ++i) { float t = vv[i] * vv[i]; s = s + t; }
    #pragma unroll
    for (int d = 1; d < 64; d <<= 1) s += __shfl_xor(s, d);
    if (lane == 0) sq[row] = s;
}

__global__ __launch_bounds__(256)
void copy_z(const float* __restrict__ z, float* __restrict__ out)
{
    size_t i4 = (size_t)blockIdx.x * 256 + threadIdx.x;
    if (i4 < (size_t)NTOK * D_ / 4) {
        float4 t = ((const float4*)z)[i4];
        out[i4*4+0] = t.x; out[i4*4+1] = t.y;
        out[i4*4+2] = t.z; out[i4*4+3] = t.w;
    }
}

__global__ __launch_bounds__(256)
void gram_kernel(const float* __restrict__ z, float* __restrict__ gram)
{
    __shared__ float Ls[16][68];
    const int s = blockIdx.x;
    const int tid = threadIdx.x;
    const int tx = tid & 15, ty = tid >> 4;
    const int arow = tid >> 2, ak4 = (tid & 3) << 2;
    float acc[4][4] = {};
    const float* zp = z + ((size_t)arow * S_ + s) * D_ + ak4;
    for (int k0 = 0; k0 < D_; k0 += 16) {
        float4 av = *(const float4*)(zp + k0);
        __syncthreads();
        Ls[ak4+0][arow] = av.x; Ls[ak4+1][arow] = av.y;
        Ls[ak4+2][arow] = av.z; Ls[ak4+3][arow] = av.w;
        __syncthreads();
        #pragma unroll
        for (int kk = 0; kk < 16; ++kk) {
            float4 a = *(const float4*)&Ls[kk][ty << 2];
            float4 b = *(const float4*)&Ls[kk][tx << 2];
            float ar[4] = {a.x,a.y,a.z,a.w};
            float br[4] = {b.x,b.y,b.z,b.w};
            #pragma unroll
            for (int i = 0; i < 4; ++i)
                #pragma unroll
                for (int j = 0; j < 4; ++j)
                    acc[i][j] = fmaf(ar[i], br[j], acc[i][j]);
        }
    }
    #pragma unroll
    for (int i = 0; i < 4; ++i) {
        float4 o = {acc[i][0], acc[i][1], acc[i][2], acc[i][3]};
        *(float4*)(gram + ((size_t)s * 64 + (ty<<2) + i) * 64 + (tx<<2)) = o;
    }
}

__global__ __launch_bounds__(64)
void cluster_kernel(const float* __restrict__ gram, const float* __restrict__ sq,
                    const int* __restrict__ y, float* __restrict__ contrib,
                    int* __restrict__ assigned, float* __restrict__ out_assigned_f)
{
#pragma clang fp contract(off)
    __shared__ float G[64][65];
    __shared__ float sqs[64];
    const int s = blockIdx.x, b = threadIdx.x;
    for (int i = b; i < 4096; i += 64)
        G[i >> 6][i & 63] = gram[(size_t)s * 4096 + i];
    sqs[b] = sq[(size_t)b * S_ + s];
    __syncthreads();

    const float sqb = sqs[b];
    float dmin = INFINITY, dsum = 0.f;
    for (int c = 0; c < 64; ++c) {
        float d = sqb + sqs[c] - 2.0f * G[b][c];
        dmin = fminf(dmin, d);
        dsum = dsum + d;
    }
    float Z = 0.f;
    for (int c = 0; c < 64; ++c) {
        float d = sqb + sqs[c] - 2.0f * G[b][c];
        float e = expf(dmin - d);
        G[b][c] = e;
        Z = Z + e;
    }
    for (int c = 0; c < 64; ++c) G[b][c] = G[b][c] / Z;

    int knn[16];
    #pragma unroll
    for (int j = 0; j < 16; ++j) {
        float bp = -1.f; int bi2 = 0;
        for (int c = 0; c < 64; ++c) {
            float pv = G[b][c];
            if (pv > bp) { bp = pv; bi2 = c; }
        }
        knn[j] = bi2;
        G[b][bi2] = -1.f;
    }
    int cmatch = 0;
    #pragma unroll
    for (int j = 0; j < 16; ++j) cmatch += (knn[j] == j) ? 1 : 0;
    int lab[16];
    #pragma unroll
    for (int j = 0; j < 16; ++j) lab[j] = y[knn[j] * S_ + s];
    int bestc = -1, bestcls = 0;
    #pragma unroll
    for (int cls = 0; cls < 16; ++cls) {
        int cc = 0;
        #pragma unroll
        for (int j = 0; j < 16; ++j) cc += (lab[j] == cls) ? 1 : 0;
        if (cc > bestc) { bestc = cc; bestcls = cls; }
    }
    const int oi = s * 64 + b;
    contrib[oi] = dsum * (float)cmatch;
    assigned[oi] = bestcls;
    out_assigned_f[oi] = (float)bestcls;
}

__global__ __launch_bounds__(256)
void finalize_kernel(const float* __restrict__ contrib, const int* __restrict__ assigned,
                     const int* __restrict__ y, float* __restrict__ dout)
{
#pragma clang fp contract(off)
    __shared__ int cm[256];
    __shared__ float red[256];
    const int tid = threadIdx.x;
    cm[tid] = 0;
    float s = 0.f;
    for (int i = tid; i < NTOK; i += 256) s = s + contrib[i];
    red[tid] = s;
    __syncthreads();
    for (int i = tid; i < NTOK; i += 256)
        atomicAdd(&cm[assigned[i] * 16 + y[i]], 1);
    __syncthreads();
    for (int st = 128; st > 0; st >>= 1) {
        if (tid < st) red[tid] = red[tid] + red[tid + st];
        __syncthreads();
    }
    if (tid == 0) {
        dout[0] = red[0];
        float sij = 0.f, sa = 0.f, sb = 0.f;
        for (int i = 0; i < 256; ++i) {
            float mm = (float)cm[i];
            sij = sij + mm * (mm - 1.0f) * 0.5f;
        }
        for (int r = 0; r < 16; ++r) {
            int rs = 0;
            for (int c2 = 0; c2 < 16; ++c2) rs += cm[r * 16 + c2];
            float mm = (float)rs;
            sa = sa + mm * (mm - 1.0f) * 0.5f;
        }
        for (int c2 = 0; c2 < 16; ++c2) {
            int cs = 0;
            for (int r = 0; r < 16; ++r) cs += cm[r * 16 + c2];
            float mm = (float)cs;
            sb = sb + mm * (mm - 1.0f) * 0.5f;
        }
        float n = 16384.0f;
        float expv = sa * sb / (n * (n - 1.0f) * 0.5f);
        float mx = 0.5f * (sa + sb);
        dout[1] = (sij - expv) / (mx - expv);
    }
}

// ---------------------------------------------------------------------------
extern "C" void kernel_launch(void* const* d_in, const int* in_sizes, int n_in,
                              void* d_out, int out_size, void* d_ws, size_t ws_size,
                              hipStream_t stream)
{
    (void)in_sizes; (void)n_in; (void)out_size; (void)ws_size;
    const float* x     = (const float*)d_in[0];
    const float* W_emb = (const float*)d_in[1];
    const float* b_emb = (const float*)d_in[2];
    const float* Wq    = (const float*)d_in[3];
    const float* bq    = (const float*)d_in[4];
    const float* Wk    = (const float*)d_in[5];
    const float* bk    = (const float*)d_in[6];
    const float* Wv    = (const float*)d_in[7];
    const float* bv    = (const float*)d_in[8];
    const float* Wo    = (const float*)d_in[9];
    const float* bo    = (const float*)d_in[10];
    const float* ln1_s = (const float*)d_in[11];
    const float* ln1_b = (const float*)d_in[12];
    const float* W1    = (const float*)d_in[13];
    const float* b1    = (const float*)d_in[14];
    const float* W2    = (const float*)d_in[15];
    const float* b2    = (const float*)d_in[16];
    const float* ln2_s = (const float*)d_in[17];
    const float* ln2_b = (const float*)d_in[18];
    const float* e1_w  = (const float*)d_in[19];
    const float* e1_b  = (const float*)d_in[20];
    const float* e2_w  = (const float*)d_in[21];
    const float* e2_b  = (const float*)d_in[22];
    const float* d1_w  = (const float*)d_in[23];
    const float* d1_b  = (const float*)d_in[24];
    const float* d2_w  = (const float*)d_in[25];
    const float* d2_b  = (const float*)d_in[26];
    const int*   y     = (const int*)d_in[27];

    float* ws = (float*)d_ws;
    float*  h    = ws;                                   // 8388608
    ushort* hhi  = (ushort*)(ws + 8388608);
    ushort* hlo  = (ushort*)(ws + 12582912);
    float*  SCR  = ws + 16777216;                        // 20971520 slots scratch
    ushort* obhi = (ushort*)(ws + 37748736);
    ushort* oblo = (ushort*)(ws + 41943040);
    float*  wt   = ws + 46137344;
    ushort* WTQKV_HI = (ushort*)wt;
    ushort* WTQKV_LO = WTQKV_HI + 786432;
    ushort* WTO_HI   = WTQKV_LO + 786432;
    ushort* WTO_LO   = WTO_HI + 262144;
    ushort* WT1_HI   = WTO_LO + 262144;
    ushort* WT1_LO   = WT1_HI + 1048576;
    ushort* WT2_HI   = WT1_LO + 1048576;
    ushort* WT2_LO   = WT2_HI + 1048576;
    ushort* WE1_HI   = WT2_LO + 1048576;
    ushort* WE1_LO   = WE1_HI + 65536;
    ushort* WE2_HI   = WE1_LO + 65536;
    ushort* WE2_LO   = WE2_HI + 65536;
    ushort* WD1_HI   = WE2_LO + 65536;
    ushort* WD1_LO   = WD1_HI + 65536;
    ushort* WD2_HI   = WD1_LO + 65536;
    ushort* WD2_LO   = WD2_HI + 65536;
    float*  biasqkv  = ws + 49545216;

    // attention-phase overlays: P now lives where S used to be (S eliminated)
    ushort* Phi_  = (ushort*)SCR;                        // [0 .. 4.2M slots)
    ushort* Plo_  = (ushort*)(SCR + 4194304);            // [.. 8.4M)
    ushort* qkvhi = (ushort*)(SCR + 8388608);            // [.. 11.5M)
    ushort* qkvlo = (ushort*)(SCR + 11534336);           // [.. 14.7M)
    ushort* VThi  = (ushort*)(SCR + 14680064);           // [.. 15.7M)
    ushort* VTlo  = (ushort*)(SCR + 15728640);           // [.. 16.8M)
    // post-attention / FFN phase:
    float*  Of32  = SCR;
    ushort* f1hi  = (ushort*)SCR;
    ushort* f1lo  = (ushort*)(SCR + 8388608);
    float*  Xhalf = SCR + 16777216;
    // cluster phase:
    ushort* enchi = (ushort*)SCR;
    ushort* enclo = (ushort*)(SCR + 4194304);
    float*  z     = SCR + 8388608;
    float*  gram  = SCR + 16777216;
    float*  sqb_  = SCR + 17825792;
    float*  contrib = SCR + 17842176;
    int*    assigned = (int*)(SCR + 17858560);
    ushort* t1hi = obhi;
    ushort* t1lo = oblo;
    ushort* t2hi = obhi + 2097152;
    ushort* t2lo = oblo + 2097152;
    float*  dout = (float*)d_out;

    dim3 blk(256);
    auto gg = [](int M, int N) { return dim3(N >> 7, M >> 7); };

    transpose_split<<<dim3(2, 8), blk, 0, stream>>>(e1_w, WE1_HI, WE1_LO, 512, 128);
    transpose_split<<<dim3(8, 2), blk, 0, stream>>>(e2_w, WE2_HI, WE2_LO, 128, 512);
    transpose_split<<<dim3(2, 8), blk, 0, stream>>>(d1_w, WD1_HI, WD1_LO, 512, 128);
    transpose_split<<<dim3(8, 2), blk, 0, stream>>>(d2_w, WD2_HI, WD2_LO, 128, 512);

    gemm_f32<<<dim3(8, 256), blk, 0, stream>>>(x, W_emb, b_emb, h, hhi, hlo, NTOK, D_, IN_);

    for (int l = 0; l < L_; ++l) {
        transpose_split<<<dim3(8, 8), blk, 0, stream>>>(Wq + (size_t)l*D_*D_, WTQKV_HI,            WTQKV_LO,            512, 512);
        transpose_split<<<dim3(8, 8), blk, 0, stream>>>(Wk + (size_t)l*D_*D_, WTQKV_HI + 512*512,  WTQKV_LO + 512*512,  512, 512);
        transpose_split<<<dim3(8, 8), blk, 0, stream>>>(Wv + (size_t)l*D_*D_, WTQKV_HI + 1024*512, WTQKV_LO + 1024*512, 512, 512);
        transpose_split<<<dim3(8, 8), blk, 0, stream>>>(Wo + (size_t)l*D_*D_, WTO_HI, WTO_LO, 512, 512);
        transpose_split<<<dim3(32, 8), blk, 0, stream>>>(W1 + (size_t)l*D_*DFF_, WT1_HI, WT1_LO, 512, 2048);
        transpose_split<<<dim3(8, 32), blk, 0, stream>>>(W2 + (size_t)l*DFF_*D_, WT2_HI, WT2_LO, 2048, 512);
        concat3<<<dim3(6), blk, 0, stream>>>(bq + l*D_, bk + l*D_, bv + l*D_, biasqkv);

        for (int qtr = 0; qtr < 4; ++qtr) {
            const size_t hoff = (size_t)qtr * 4096 * 512;
            gemm3<2><<<gg(4096, 1536), blk, 0, stream>>>(
                hhi + hoff, hlo + hoff, WTQKV_HI, WTQKV_LO, biasqkv,
                nullptr, qkvhi, qkvlo, 4096, 1536, 512);
            vtrans<<<dim3(128), blk, 0, stream>>>(qkvhi, qkvlo, VThi, VTlo);
            qks_gemm<<<dim3(2, 128), blk, 0, stream>>>(qkvhi, qkvlo, Phi_, Plo_);
            pv_gemm<<<dim3(2, 128), blk, 0, stream>>>(Phi_, Plo_, VThi, VTlo,
                                                      obhi, oblo, qtr * 4096);
        }
        gemm3<0><<<gg(NTOK, 512), blk, 0, stream>>>(
            obhi, oblo, WTO_HI, WTO_LO, bo + l*D_,
            Of32, nullptr, nullptr, NTOK, 512, 512);
        ln_res<<<dim3(NTOK / 4), blk, 0, stream>>>(h, Of32, ln1_s + l*D_, ln1_b + l*D_, hhi, hlo);

        for (int half = 0; half < 2; ++half) {
            const size_t ro = (size_t)half * HALF_ * D_;
            gemm3<3><<<gg(HALF_, DFF_), blk, 0, stream>>>(
                hhi + ro, hlo + ro, WT1_HI, WT1_LO, b1 + l*DFF_,
                nullptr, f1hi, f1lo, HALF_, 2048, 512);
            gemm3<0><<<gg(HALF_, 512), blk, 0, stream>>>(
                f1hi, f1lo, WT2_HI, WT2_LO, b2 + l*D_,
                Xhalf, nullptr, nullptr, HALF_, 512, 2048);
            ln_res<<<dim3(HALF_ / 4), blk, 0, stream>>>(
                h + ro, Xhalf, ln2_s + l*D_, ln2_b + l*D_, hhi + ro, hlo + ro);
        }
    }

    gemm3<3><<<gg(NTOK, 128), blk, 0, stream>>>(
        hhi, hlo, WE1_HI, WE1_LO, e1_b, nullptr, t1hi, t1lo, NTOK, 128, 512);
    gemm3<2><<<gg(NTOK, 512), blk, 0, stream>>>(
        t1hi, t1lo, WE2_HI, WE2_LO, e2_b, nullptr, enchi, enclo, NTOK, 512, 128);
    gemm3<3><<<gg(NTOK, 128), blk, 0, stream>>>(
        enchi, enclo, WD1_HI, WD1_LO, d1_b, nullptr, t2hi, t2lo, NTOK, 128, 512);
    gemm3<0><<<gg(NTOK, 512), blk, 0, stream>>>(
        t2hi, t2lo, WD2_HI, WD2_LO, d2_b, z, nullptr, nullptr, NTOK, 512, 128);

    copy_z<<<dim3(NTOK * D_ / 4 / 256), blk, 0, stream>>>(z, dout + 16386);
    sq_kernel<<<dim3(NTOK), dim3(64), 0, stream>>>(z, sqb_);
    gram_kernel<<<dim3(S_), blk, 0, stream>>>(z, gram);
    cluster_kernel<<<dim3(S_), dim3(64), 0, stream>>>(gram, sqb_, y, contrib, assigned, dout + 2);
    finalize_kernel<<<dim3(1), blk, 0, stream>>>(contrib, assigned, y, dout);
}

// Round 11
// 1440.678 us; speedup vs baseline: 1.1635x; 1.0409x over previous
//
#include <hip/hip_runtime.h>
#include <cstdint>
#include <cmath>

#define B_ 64
#define S_ 256
#define IN_ 32
#define D_ 512
#define H_ 8
#define L_ 2
#define DFF_ 2048
#define C_ 16
#define DH_ 64
#define NTOK (B_*S_)   // 16384
#define HALF_ 8192

typedef __attribute__((ext_vector_type(8))) short bf16x8;
typedef __attribute__((ext_vector_type(4))) float f32x4;
typedef __attribute__((ext_vector_type(8))) ushort ushortx8;

__device__ __forceinline__ ushort bf16_rn(float x) {
    union { float f; uint32_t u; } v; v.f = x;
    uint32_t r = v.u + 0x7fffu + ((v.u >> 16) & 1u);
    return (ushort)(r >> 16);
}
__device__ __forceinline__ float bf16_f32(ushort h) {
    union { uint32_t u; float f; } v; v.u = ((uint32_t)h) << 16;
    return v.f;
}

#define GLDS(gp, lp) __builtin_amdgcn_global_load_lds( \
    (const __attribute__((address_space(1))) void*)(gp), \
    (__attribute__((address_space(3))) void*)(lp), 16, 0, 0)

// XCD-chunk bijective swizzle (nwg % 8 == 0 for all users).
__device__ __forceinline__ int xcd_swz(int lid, int nwg) {
    return (lid & 7) * (nwg >> 3) + (lid >> 3);
}

// ---------------------------------------------------------------------------
// Merged bf16x3 GEMM (128x128, 2-phase, counted vmcnt). All 4 operand streams
// staged once per K-tile (48 MFMA : 16 ds_read_b128), 64 KB LDS dbuf.
// MODE: 0 = f32 out, 2 = split hi/lo out, 3 = split + ReLU.
// ---------------------------------------------------------------------------
template<int MODE>
__global__ __launch_bounds__(256)
void gemm3(const ushort* __restrict__ Ahi, const ushort* __restrict__ Alo,
           const ushort* __restrict__ Bhi, const ushort* __restrict__ Blo,
           const float* __restrict__ bias,
           float* __restrict__ Cf, ushort* __restrict__ Chi, ushort* __restrict__ Clo,
           int M, int N, int K)
{
    __shared__ __align__(16) ushort Als[2][2][128*32];
    __shared__ __align__(16) ushort Bls[2][2][128*32];
    const int tid  = threadIdx.x;
    const int wave = tid >> 6, lane = tid & 63;
    const int nwg = gridDim.x * gridDim.y;
    const int swz = xcd_swz(blockIdx.y * gridDim.x + blockIdx.x, nwg);
    const int m0 = (swz / gridDim.x) << 7, n0 = (swz % gridDim.x) << 7;
    const int wr = wave >> 1, wc = wave & 1;

    const ushort* Ah = Ahi + (size_t)m0 * K;
    const ushort* Al = Alo + (size_t)m0 * K;
    const ushort* Bh = Bhi + (size_t)n0 * K;
    const ushort* Bl = Blo + (size_t)n0 * K;

    const int KT = K >> 5;

    f32x4 acc[4][4];
    #pragma unroll
    for (int m = 0; m < 4; ++m)
        #pragma unroll
        for (int n = 0; n < 4; ++n)
            acc[m][n] = (f32x4){0.f, 0.f, 0.f, 0.f};

    auto stage = [&](int buf, int kk) {
        #pragma unroll
        for (int i = 0; i < 2; ++i) {
            const int rbase = wave * 32 + i * 16;
            const int row   = rbase + (lane >> 2);
            const int slot  = (lane & 3) ^ ((row >> 1) & 3);
            GLDS(Ah + (size_t)row * K + kk + slot * 8, &Als[buf][0][rbase * 32]);
            GLDS(Al + (size_t)row * K + kk + slot * 8, &Als[buf][1][rbase * 32]);
            GLDS(Bh + (size_t)row * K + kk + slot * 8, &Bls[buf][0][rbase * 32]);
            GLDS(Bl + (size_t)row * K + kk + slot * 8, &Bls[buf][1][rbase * 32]);
        }
    };

    stage(0, 0);
    for (int t = 0; t < KT; ++t) {
        const int buf = t & 1;
        if (t + 1 < KT) {
            stage(buf ^ 1, (t + 1) << 5);
            asm volatile("s_waitcnt vmcnt(8)" ::: "memory");
        } else {
            asm volatile("s_waitcnt vmcnt(0)" ::: "memory");
        }
        __builtin_amdgcn_sched_barrier(0);
        __builtin_amdgcn_s_barrier();

        const int chunk = lane >> 4;
        bf16x8 afh[4], afl[4], bfh[4], bfl[4];
        #pragma unroll
        for (int m = 0; m < 4; ++m) {
            const int row = wr * 64 + m * 16 + (lane & 15);
            const int sl  = chunk ^ ((row >> 1) & 3);
            afh[m] = *(const bf16x8*)(&Als[buf][0][row * 32 + sl * 8]);
            afl[m] = *(const bf16x8*)(&Als[buf][1][row * 32 + sl * 8]);
        }
        #pragma unroll
        for (int n = 0; n < 4; ++n) {
            const int row = wc * 64 + n * 16 + (lane & 15);
            const int sl  = chunk ^ ((row >> 1) & 3);
            bfh[n] = *(const bf16x8*)(&Bls[buf][0][row * 32 + sl * 8]);
            bfl[n] = *(const bf16x8*)(&Bls[buf][1][row * 32 + sl * 8]);
        }
        #pragma unroll
        for (int m = 0; m < 4; ++m)
            #pragma unroll
            for (int n = 0; n < 4; ++n) {
                acc[m][n] = __builtin_amdgcn_mfma_f32_16x16x32_bf16(afh[m], bfh[n], acc[m][n], 0, 0, 0);
                acc[m][n] = __builtin_amdgcn_mfma_f32_16x16x32_bf16(afh[m], bfl[n], acc[m][n], 0, 0, 0);
                acc[m][n] = __builtin_amdgcn_mfma_f32_16x16x32_bf16(afl[m], bfh[n], acc[m][n], 0, 0, 0);
            }
        __builtin_amdgcn_sched_barrier(0);
        __builtin_amdgcn_s_barrier();
    }

    const int col_l = lane & 15;
    float bv[4];
    #pragma unroll
    for (int n = 0; n < 4; ++n) bv[n] = bias[n0 + wc * 64 + n * 16 + col_l];
    #pragma unroll
    for (int m = 0; m < 4; ++m) {
        #pragma unroll
        for (int j = 0; j < 4; ++j) {
            const size_t grow = (size_t)(m0 + wr * 64 + m * 16 + (lane >> 4) * 4 + j);
            #pragma unroll
            for (int n = 0; n < 4; ++n) {
                float x = acc[m][n][j] + bv[n];
                if (MODE & 1) x = fmaxf(x, 0.f);
                const size_t gidx = grow * N + (n0 + wc * 64 + n * 16 + col_l);
                if (MODE < 2) {
                    Cf[gidx] = x;
                } else {
                    ushort hb = bf16_rn(x);
                    Chi[gidx] = hb;
                    Clo[gidx] = bf16_rn(x - bf16_f32(hb));
                }
            }
        }
    }
}

// ---------------------------------------------------------------------------
// Fused QK^T + row-softmax (bf16x3) + V-transpose epilogue.
// Block = (bh, qt): full 128q x 256k score tile; wave owns 32q rows (full k).
// After P is written, the block transposes V rows [qt*128, +128) of its bh
// into VT (reusing the dead Qls LDS region). grid = (2 [qt], 128 [bh]).
// ---------------------------------------------------------------------------
__global__ __launch_bounds__(256)
void qks_gemm(const ushort* __restrict__ qkvhi, const ushort* __restrict__ qkvlo,
              ushort* __restrict__ Phi, ushort* __restrict__ Plo,
              ushort* __restrict__ VThi, ushort* __restrict__ VTlo)
{
    __shared__ __align__(16) ushort Qls[2][128*64];   // [hi/lo][row*64]
    __shared__ __align__(16) ushort Kls[2][128*64];
    const int tid = threadIdx.x, wave = tid >> 6, lane = tid & 63;
    const int swz = xcd_swz(blockIdx.y * 2 + blockIdx.x, 256);
    const int bh = swz >> 1, qt = swz & 1;
    const int b = bh >> 3, h = bh & 7;

    const ushort* Qh = qkvhi + ((size_t)(b * 256 + qt * 128)) * 1536 + h * 64;
    const ushort* Ql = qkvlo + ((size_t)(b * 256 + qt * 128)) * 1536 + h * 64;
    const ushort* Kh = qkvhi + ((size_t)(b * 256)) * 1536 + 512 + h * 64;
    const ushort* Kl = qkvlo + ((size_t)(b * 256)) * 1536 + 512 + h * 64;

    auto stage128 = [&](const ushort* src, ushort* dst) {
        #pragma unroll
        for (int j = 0; j < 4; ++j) {
            const int rl   = j * 32 + wave * 8 + (lane >> 3);
            const int slot = (lane & 7) ^ (rl & 7);
            GLDS(src + (size_t)rl * 1536 + slot * 8, dst + (j * 32 + wave * 8) * 64);
        }
    };

    f32x4 acc[2][16];
    #pragma unroll
    for (int mi = 0; mi < 2; ++mi)
        #pragma unroll
        for (int nj = 0; nj < 16; ++nj)
            acc[mi][nj] = (f32x4){0.f, 0.f, 0.f, 0.f};

    stage128(Qh, &Qls[0][0]);
    stage128(Ql, &Qls[1][0]);
    stage128(Kh, &Kls[0][0]);
    stage128(Kl, &Kls[1][0]);
    asm volatile("s_waitcnt vmcnt(0)" ::: "memory");
    __builtin_amdgcn_sched_barrier(0);
    __builtin_amdgcn_s_barrier();

    // Q fragments held for the whole kernel
    bf16x8 qh[2][2], ql[2][2];
    #pragma unroll
    for (int mi = 0; mi < 2; ++mi)
        #pragma unroll
        for (int ks = 0; ks < 2; ++ks) {
            const int row = wave * 32 + mi * 16 + (lane & 15);
            const int es  = (ks * 4 + (lane >> 4)) ^ (lane & 7);
            qh[mi][ks] = *(const bf16x8*)&Qls[0][row * 64 + es * 8];
            ql[mi][ks] = *(const bf16x8*)&Qls[1][row * 64 + es * 8];
        }

    #pragma unroll
    for (int hk = 0; hk < 2; ++hk) {
        if (hk == 1) {
            __syncthreads();                       // all reads of K-half0 done
            stage128(Kh + (size_t)128 * 1536, &Kls[0][0]);
            stage128(Kl + (size_t)128 * 1536, &Kls[1][0]);
            asm volatile("s_waitcnt vmcnt(0)" ::: "memory");
            __builtin_amdgcn_sched_barrier(0);
            __builtin_amdgcn_s_barrier();
        }
        #pragma unroll
        for (int ng = 0; ng < 2; ++ng) {
            bf16x8 kh[4][2], kl[4][2];
            #pragma unroll
            for (int nj = 0; nj < 4; ++nj)
                #pragma unroll
                for (int ks = 0; ks < 2; ++ks) {
                    const int row = (ng * 4 + nj) * 16 + (lane & 15);
                    const int es  = (ks * 4 + (lane >> 4)) ^ (lane & 7);
                    kh[nj][ks] = *(const bf16x8*)&Kls[0][row * 64 + es * 8];
                    kl[nj][ks] = *(const bf16x8*)&Kls[1][row * 64 + es * 8];
                }
            #pragma unroll
            for (int mi = 0; mi < 2; ++mi)
                #pragma unroll
                for (int nj = 0; nj < 4; ++nj) {
                    const int an = hk * 8 + ng * 4 + nj;
                    #pragma unroll
                    for (int ks = 0; ks < 2; ++ks) {
                        acc[mi][an] = __builtin_amdgcn_mfma_f32_16x16x32_bf16(qh[mi][ks], kh[nj][ks], acc[mi][an], 0, 0, 0);
                        acc[mi][an] = __builtin_amdgcn_mfma_f32_16x16x32_bf16(qh[mi][ks], kl[nj][ks], acc[mi][an], 0, 0, 0);
                        acc[mi][an] = __builtin_amdgcn_mfma_f32_16x16x32_bf16(ql[mi][ks], kh[nj][ks], acc[mi][an], 0, 0, 0);
                    }
                }
        }
    }

    // row softmax + split-bf16 P write
    const int colb = lane & 15;
    #pragma unroll
    for (int mi = 0; mi < 2; ++mi) {
        #pragma unroll
        for (int j = 0; j < 4; ++j) {
            float v[16];
            float mx = -INFINITY;
            #pragma unroll
            for (int nj = 0; nj < 16; ++nj) {
                v[nj] = acc[mi][nj][j] * 0.125f;
                mx = fmaxf(mx, v[nj]);
            }
            #pragma unroll
            for (int d = 1; d < 16; d <<= 1) mx = fmaxf(mx, __shfl_xor(mx, d));
            float sum = 0.f;
            #pragma unroll
            for (int nj = 0; nj < 16; ++nj) {
                v[nj] = expf(v[nj] - mx);
                sum += v[nj];
            }
            #pragma unroll
            for (int d = 1; d < 16; d <<= 1) sum += __shfl_xor(sum, d);
            const float inv = 1.0f / sum;
            const int qrow = qt * 128 + wave * 32 + mi * 16 + (lane >> 4) * 4 + j;
            const size_t base = ((size_t)bh * 256 + qrow) * 256;
            #pragma unroll
            for (int nj = 0; nj < 16; ++nj) {
                float p = v[nj] * inv;
                ushort hb = bf16_rn(p);
                Phi[base + nj * 16 + colb] = hb;
                Plo[base + nj * 16 + colb] = bf16_rn(p - bf16_f32(hb));
            }
        }
    }

    // ---- fused V-transpose: rows [qt*128, +128) of this bh -> VT ----------
    // Qls (32 KB contiguous) is dead after the Q-frag loads; reuse as tile.
    // Tile layout: T[dh (0..63)][key (0..127)], row stride 144 (breaks pow2).
    {
        ushort* T = &Qls[0][0];            // 64*144 = 9216 ushorts < 16384
        const int TP = 144;
        const ushort* vsrcs[2] = {
            qkvhi + ((size_t)(b * 256 + qt * 128)) * 1536 + 1024 + h * 64,
            qkvlo + ((size_t)(b * 256 + qt * 128)) * 1536 + 1024 + h * 64 };
        ushort* vdsts[2] = { VThi, VTlo };
        #pragma unroll
        for (int pass = 0; pass < 2; ++pass) {
            __syncthreads();
            if (tid < 128) {                        // tid = key within half
                const ushort* p = vsrcs[pass] + (size_t)tid * 1536;
                #pragma unroll
                for (int i = 0; i < 8; ++i) {
                    ushortx8 vv = *(const ushortx8*)(p + i * 8);
                    #pragma unroll
                    for (int j = 0; j < 8; ++j) T[(i * 8 + j) * TP + tid] = vv[j];
                }
            }
            __syncthreads();
            {
                const int dh = tid >> 2;            // 0..63
                const int kseg = (tid & 3) * 32;    // 0,32,64,96
                ushort* op = vdsts[pass] + ((size_t)bh * 64 + dh) * 256 + qt * 128 + kseg;
                #pragma unroll
                for (int i = 0; i < 4; ++i) {
                    ushortx8 vv;
                    #pragma unroll
                    for (int j = 0; j < 8; ++j) vv[j] = T[dh * TP + kseg + i * 8 + j];
                    *(ushortx8*)(op + i * 8) = vv;
                }
            }
        }
    }
}

// ---------------------------------------------------------------------------
// Batched PV: O[q][dh] = P[q][:] . V[:, dh] (bf16x3), O written split hi/lo.
// grid = (2 [qt], 128 [bh]). Tile 128x64.
// ---------------------------------------------------------------------------
__global__ __launch_bounds__(256)
void pv_gemm(const ushort* __restrict__ Phi, const ushort* __restrict__ Plo,
             const ushort* __restrict__ VThi, const ushort* __restrict__ VTlo,
             ushort* __restrict__ obhi, ushort* __restrict__ oblo, int t0)
{
    __shared__ __align__(16) ushort Als[2][2][128*32];
    __shared__ __align__(16) ushort Bls[2][2][64*32];
    const int tid = threadIdx.x, wave = tid >> 6, lane = tid & 63;
    const int swz = xcd_swz(blockIdx.y * 2 + blockIdx.x, 256);
    const int bh = swz >> 1, qt = swz & 1;
    const ushort* Ah = Phi + ((size_t)bh * 256 + qt * 128) * 256;
    const ushort* Al = Plo + ((size_t)bh * 256 + qt * 128) * 256;
    const ushort* Bh = VThi + (size_t)bh * 64 * 256;
    const ushort* Bl = VTlo + (size_t)bh * 64 * 256;

    f32x4 acc[2][4];
    #pragma unroll
    for (int m = 0; m < 2; ++m)
        #pragma unroll
        for (int n = 0; n < 4; ++n)
            acc[m][n] = (f32x4){0.f, 0.f, 0.f, 0.f};

    auto stage = [&](int buf, int kk) {
        #pragma unroll
        for (int i = 0; i < 2; ++i) {
            const int rbase = wave * 32 + i * 16;
            const int row   = rbase + (lane >> 2);
            const int slot  = (lane & 3) ^ ((row >> 1) & 3);
            GLDS(Ah + (size_t)row * 256 + kk + slot * 8, &Als[buf][0][rbase * 32]);
            GLDS(Al + (size_t)row * 256 + kk + slot * 8, &Als[buf][1][rbase * 32]);
        }
        const int rbase2 = wave * 16;
        const int row2   = rbase2 + (lane >> 2);
        const int slot2  = (lane & 3) ^ ((row2 >> 1) & 3);
        GLDS(Bh + (size_t)row2 * 256 + kk + slot2 * 8, &Bls[buf][0][rbase2 * 32]);
        GLDS(Bl + (size_t)row2 * 256 + kk + slot2 * 8, &Bls[buf][1][rbase2 * 32]);
    };

    stage(0, 0);
    for (int t = 0; t < 8; ++t) {
        const int buf = t & 1;
        __syncthreads();
        if (t < 7) stage(buf ^ 1, (t + 1) << 5);
        const int chunk = lane >> 4;
        bf16x8 afh[2], afl[2], bfh[4], bfl[4];
        #pragma unroll
        for (int m = 0; m < 2; ++m) {
            const int row = wave * 32 + m * 16 + (lane & 15);
            const int sl  = chunk ^ ((row >> 1) & 3);
            afh[m] = *(const bf16x8*)(&Als[buf][0][row * 32 + sl * 8]);
            afl[m] = *(const bf16x8*)(&Als[buf][1][row * 32 + sl * 8]);
        }
        #pragma unroll
        for (int n = 0; n < 4; ++n) {
            const int row = n * 16 + (lane & 15);
            const int sl  = chunk ^ ((row >> 1) & 3);
            bfh[n] = *(const bf16x8*)(&Bls[buf][0][row * 32 + sl * 8]);
            bfl[n] = *(const bf16x8*)(&Bls[buf][1][row * 32 + sl * 8]);
        }
        #pragma unroll
        for (int m = 0; m < 2; ++m)
            #pragma unroll
            for (int n = 0; n < 4; ++n) {
                acc[m][n] = __builtin_amdgcn_mfma_f32_16x16x32_bf16(afh[m], bfh[n], acc[m][n], 0, 0, 0);
                acc[m][n] = __builtin_amdgcn_mfma_f32_16x16x32_bf16(afh[m], bfl[n], acc[m][n], 0, 0, 0);
                acc[m][n] = __builtin_amdgcn_mfma_f32_16x16x32_bf16(afl[m], bfh[n], acc[m][n], 0, 0, 0);
            }
        __syncthreads();
    }

    const int b = bh >> 3, h = bh & 7;
    const int col_l = lane & 15;
    #pragma unroll
    for (int m = 0; m < 2; ++m)
        #pragma unroll
        for (int j = 0; j < 4; ++j) {
            const int q = qt * 128 + wave * 32 + m * 16 + (lane >> 4) * 4 + j;
            const size_t token = (size_t)t0 + (size_t)b * 256 + q;
            #pragma unroll
            for (int n = 0; n < 4; ++n) {
                const int col = h * 64 + n * 16 + col_l;
                float x = acc[m][n][j];
                ushort hb = bf16_rn(x);
                obhi[token * 512 + col] = hb;
                oblo[token * 512 + col] = bf16_rn(x - bf16_f32(hb));
            }
        }
}

// ---------------------------------------------------------------------------
// f32 GEMM (embedding only, K=32) with fused bf16 hi/lo split output.
// ---------------------------------------------------------------------------
__global__ __launch_bounds__(256)
void gemm_f32(const float* __restrict__ A, const float* __restrict__ W,
              const float* __restrict__ bias, float* __restrict__ Cc,
              ushort* __restrict__ Chi, ushort* __restrict__ Clo,
              int M, int N, int K)
{
    __shared__ float As[16][68];
    __shared__ float Bs[16][64];
    const int tid = threadIdx.x;
    const int tx = tid & 15, ty = tid >> 4;
    const int m0 = blockIdx.y << 6, n0 = blockIdx.x << 6;
    const int arow = tid >> 2, ak4 = (tid & 3) << 2;
    const int brow = tid >> 4, bc4 = (tid & 15) << 2;
    float acc[4][4] = {};
    const float* aptr = A + (size_t)(m0 + arow) * K + ak4;
    const float* bptr = W + (size_t)brow * N + n0 + bc4;
    for (int k0 = 0; k0 < K; k0 += 16) {
        float4 av = *(const float4*)(aptr + k0);
        float4 bv = *(const float4*)(bptr + (size_t)k0 * N);
        __syncthreads();
        As[ak4+0][arow] = av.x; As[ak4+1][arow] = av.y;
        As[ak4+2][arow] = av.z; As[ak4+3][arow] = av.w;
        *(float4*)&Bs[brow][bc4] = bv;
        __syncthreads();
        #pragma unroll
        for (int kk = 0; kk < 16; ++kk) {
            float4 a = *(const float4*)&As[kk][ty << 2];
            float4 b = *(const float4*)&Bs[kk][tx << 2];
            float ar[4] = {a.x,a.y,a.z,a.w};
            float br[4] = {b.x,b.y,b.z,b.w};
            #pragma unroll
            for (int i = 0; i < 4; ++i)
                #pragma unroll
                for (int j = 0; j < 4; ++j)
                    acc[i][j] = fmaf(ar[i], br[j], acc[i][j]);
        }
    }
    float4 bb = *(const float4*)(bias + n0 + (tx << 2));
    #pragma unroll
    for (int i = 0; i < 4; ++i) {
        int m = m0 + (ty << 2) + i;
        float o[4];
        o[0] = acc[i][0] + bb.x; o[1] = acc[i][1] + bb.y;
        o[2] = acc[i][2] + bb.z; o[3] = acc[i][3] + bb.w;
        ushort4 hh, ll;
        hh.x = bf16_rn(o[0]); ll.x = bf16_rn(o[0] - bf16_f32(hh.x));
        hh.y = bf16_rn(o[1]); ll.y = bf16_rn(o[1] - bf16_f32(hh.y));
        hh.z = bf16_rn(o[2]); ll.z = bf16_rn(o[2] - bf16_f32(hh.z));
        hh.w = bf16_rn(o[3]); ll.w = bf16_rn(o[3] - bf16_f32(hh.w));
        const size_t base = (size_t)m * N + n0 + (tx << 2);
        *(float4*)(Cc + base) = (float4){o[0],o[1],o[2],o[3]};
        *(ushort4*)(Chi + base) = hh;
        *(ushort4*)(Clo + base) = ll;
    }
}

// ---------------------------------------------------------------------------
// Per-layer weight prep: all 6 transposes + qkv-bias concat in ONE dispatch.
// blocks [0,192): Wq/Wk/Wv (8x8 each); [192,256): Wo; [256,512): W1 (32x8);
// [512,768): W2 (8x32); [768,774): bias concat.
// ---------------------------------------------------------------------------
__global__ __launch_bounds__(256)
void prep_layer(const float* __restrict__ Wq, const float* __restrict__ Wk,
                const float* __restrict__ Wv, const float* __restrict__ Wo,
                const float* __restrict__ W1, const float* __restrict__ W2,
                const float* __restrict__ bq, const float* __restrict__ bk,
                const float* __restrict__ bv,
                ushort* __restrict__ WTQKV_HI, ushort* __restrict__ WTQKV_LO,
                ushort* __restrict__ WTO_HI, ushort* __restrict__ WTO_LO,
                ushort* __restrict__ WT1_HI, ushort* __restrict__ WT1_LO,
                ushort* __restrict__ WT2_HI, ushort* __restrict__ WT2_LO,
                float* __restrict__ biasqkv)
{
    __shared__ float T[64][65];
    const int blk = blockIdx.x;
    const int tid = threadIdx.x;
    if (blk >= 768) {
        int i = (blk - 768) * 256 + tid;
        biasqkv[i] = (i < 512) ? bq[i] : (i < 1024 ? bk[i - 512] : bv[i - 1024]);
        return;
    }
    const float* W; ushort* Thi; ushort* Tlo; int K, N, bx, by;
    if (blk < 192) {
        const int wsel = blk / 64, idx = blk % 64;
        W = (wsel == 0) ? Wq : ((wsel == 1) ? Wk : Wv);
        Thi = WTQKV_HI + (size_t)wsel * 512 * 512;
        Tlo = WTQKV_LO + (size_t)wsel * 512 * 512;
        K = 512; N = 512; bx = idx % 8; by = idx / 8;
    } else if (blk < 256) {
        const int idx = blk - 192;
        W = Wo; Thi = WTO_HI; Tlo = WTO_LO;
        K = 512; N = 512; bx = idx % 8; by = idx / 8;
    } else if (blk < 512) {
        const int idx = blk - 256;
        W = W1; Thi = WT1_HI; Tlo = WT1_LO;
        K = 512; N = 2048; bx = idx % 32; by = idx / 32;
    } else {
        const int idx = blk - 512;
        W = W2; Thi = WT2_HI; Tlo = WT2_LO;
        K = 2048; N = 512; bx = idx % 8; by = idx / 8;
    }
    const int k0 = by << 6, n0 = bx << 6;
    #pragma unroll
    for (int i = 0; i < 16; ++i) {
        int idx = tid + i * 256;
        int kl = idx >> 6, nl = idx & 63;
        T[nl][kl] = W[(size_t)(k0 + kl) * N + n0 + nl];
    }
    __syncthreads();
    #pragma unroll
    for (int i = 0; i < 16; ++i) {
        int idx = tid + i * 256;
        int nl = idx >> 6, kl = idx & 63;
        float x = T[nl][kl];
        ushort hb = bf16_rn(x);
        size_t o = (size_t)(n0 + nl) * K + k0 + kl;
        Thi[o] = hb;
        Tlo[o] = bf16_rn(x - bf16_f32(hb));
    }
}

__global__ __launch_bounds__(256)
void transpose_split(const float* __restrict__ W, ushort* __restrict__ Thi,
                     ushort* __restrict__ Tlo, int K, int N)
{
    __shared__ float T[64][65];
    const int k0 = blockIdx.y << 6, n0 = blockIdx.x << 6;
    const int tid = threadIdx.x;
    #pragma unroll
    for (int i = 0; i < 16; ++i) {
        int idx = tid + i * 256;
        int kl = idx >> 6, nl = idx & 63;
        T[nl][kl] = W[(size_t)(k0 + kl) * N + n0 + nl];
    }
    __syncthreads();
    #pragma unroll
    for (int i = 0; i < 16; ++i) {
        int idx = tid + i * 256;
        int nl = idx >> 6, kl = idx & 63;
        float x = T[nl][kl];
        ushort hb = bf16_rn(x);
        size_t o = (size_t)(n0 + nl) * K + k0 + kl;
        Thi[o] = hb;
        Tlo[o] = bf16_rn(x - bf16_f32(hb));
    }
}

// ---------------------------------------------------------------------------
// residual + LN: 4 rows per 256-thread block (one wave per row).
// ---------------------------------------------------------------------------
__global__ __launch_bounds__(256)
void ln_res(float* __restrict__ h, const float* __restrict__ t,
            const float* __restrict__ sc, const float* __restrict__ bi,
            ushort* __restrict__ hhi, ushort* __restrict__ hlo)
{
    const int row = blockIdx.x * 4 + (threadIdx.x >> 6);
    const int lane = threadIdx.x & 63;
    const size_t off = (size_t)row * D_ + (size_t)lane * 8;
    float x[8];
    float4 a0 = *(const float4*)(h + off),  a1 = *(const float4*)(h + off + 4);
    float4 b0 = *(const float4*)(t + off),  b1 = *(const float4*)(t + off + 4);
    x[0]=a0.x+b0.x; x[1]=a0.y+b0.y; x[2]=a0.z+b0.z; x[3]=a0.w+b0.w;
    x[4]=a1.x+b1.x; x[5]=a1.y+b1.y; x[6]=a1.z+b1.z; x[7]=a1.w+b1.w;

    float s = 0.f;
    #pragma unroll
    for (int i = 0; i < 8; ++i) s += x[i];
    #pragma unroll
    for (int d = 1; d < 64; d <<= 1) s += __shfl_xor(s, d);
    float mean = s * (1.0f / 512.0f);

    float vsum = 0.f;
    #pragma unroll
    for (int i = 0; i < 8; ++i) { float dx = x[i] - mean; vsum += dx * dx; }
    #pragma unroll
    for (int d = 1; d < 64; d <<= 1) vsum += __shfl_xor(vsum, d);
    float den = sqrtf(vsum * (1.0f / 512.0f) + 1e-5f);

    float4 s0 = *(const float4*)(sc + lane*8), s1 = *(const float4*)(sc + lane*8 + 4);
    float4 c0 = *(const float4*)(bi + lane*8), c1 = *(const float4*)(bi + lane*8 + 4);
    float scv[8] = {s0.x,s0.y,s0.z,s0.w,s1.x,s1.y,s1.z,s1.w};
    float biv[8] = {c0.x,c0.y,c0.z,c0.w,c1.x,c1.y,c1.z,c1.w};
    float out[8];
    ushort hh[8], ll[8];
    #pragma unroll
    for (int i = 0; i < 8; ++i) {
        out[i] = (x[i] - mean) / den * scv[i] + biv[i];
        hh[i] = bf16_rn(out[i]);
        ll[i] = bf16_rn(out[i] - bf16_f32(hh[i]));
    }
    *(float4*)(h + off)     = (float4){out[0],out[1],out[2],out[3]};
    *(float4*)(h + off + 4) = (float4){out[4],out[5],out[6],out[7]};
    *(ushort4*)(hhi + off)     = (ushort4){hh[0],hh[1],hh[2],hh[3]};
    *(ushort4*)(hhi + off + 4) = (ushort4){hh[4],hh[5],hh[6],hh[7]};
    *(ushort4*)(hlo + off)     = (ushort4){ll[0],ll[1],ll[2],ll[3]};
    *(ushort4*)(hlo + off + 4) = (ushort4){ll[4],ll[5],ll[6],ll[7]};
}

// ---------------------------------------------------------------------------
// z -> d_out copy + sq[token] = sum(z^2), fused (z read once). 4 rows/block.
// ---------------------------------------------------------------------------
__global__ __launch_bounds__(256)
void zout_sq(const float* __restrict__ z, float* __restrict__ outz,
             float* __restrict__ sq)
{
#pragma clang fp contract(off)
    const int row = blockIdx.x * 4 + (threadIdx.x >> 6);
    const int lane = threadIdx.x & 63;
    const size_t off = (size_t)row * D_ + (size_t)lane * 8;
    const float* p = z + off;
    float4 a0 = *(const float4*)(p), a1 = *(const float4*)(p + 4);
    float vv[8] = {a0.x,a0.y,a0.z,a0.w,a1.x,a1.y,a1.z,a1.w};
    // scalar stores: outz base (dout+16386) is only 8B-aligned
    float* op = outz + off;
    #pragma unroll
    for (int i = 0; i < 8; ++i) op[i] = vv[i];
    float s = 0.f;
    #pragma unroll
    for (int i = 0; i < 8; ++i) { float t = vv[i] * vv[i]; s = s + t; }
    #pragma unroll
    for (int d = 1; d < 64; d <<= 1) s += __shfl_xor(s, d);
    if (lane == 0) sq[row] = s;
}

__global__ __launch_bounds__(256)
void gram_kernel(const float* __restrict__ z, float* __restrict__ gram)
{
    __shared__ float Ls[16][68];
    const int s = blockIdx.x;
    const int tid = threadIdx.x;
    const int tx = tid & 15, ty = tid >> 4;
    const int arow = tid >> 2, ak4 = (tid & 3) << 2;
    float acc[4][4] = {};
    const float* zp = z + ((size_t)arow * S_ + s) * D_ + ak4;
    for (int k0 = 0; k0 < D_; k0 += 16) {
        float4 av = *(const float4*)(zp + k0);
        __syncthreads();
        Ls[ak4+0][arow] = av.x; Ls[ak4+1][arow] = av.y;
        Ls[ak4+2][arow] = av.z; Ls[ak4+3][arow] = av.w;
        __syncthreads();
        #pragma unroll
        for (int kk = 0; kk < 16; ++kk) {
            float4 a = *(const float4*)&Ls[kk][ty << 2];
            float4 b = *(const float4*)&Ls[kk][tx << 2];
            float ar[4] = {a.x,a.y,a.z,a.w};
            float br[4] = {b.x,b.y,b.z,b.w};
            #pragma unroll
            for (int i = 0; i < 4; ++i)
                #pragma unroll
                for (int j = 0; j < 4; ++j)
                    acc[i][j] = fmaf(ar[i], br[j], acc[i][j]);
        }
    }
    #pragma unroll
    for (int i = 0; i < 4; ++i) {
        float4 o = {acc[i][0], acc[i][1], acc[i][2], acc[i][3]};
        *(float4*)(gram + ((size_t)s * 64 + (ty<<2) + i) * 64 + (tx<<2)) = o;
    }
}

__global__ __launch_bounds__(64)
void cluster_kernel(const float* __restrict__ gram, const float* __restrict__ sq,
                    const int* __restrict__ y, float* __restrict__ contrib,
                    int* __restrict__ assigned, float* __restrict__ out_assigned_f)
{
#pragma clang fp contract(off)
    __shared__ float G[64][65];
    __shared__ float sqs[64];
    const int s = blockIdx.x, b = threadIdx.x;
    for (int i = b; i < 4096; i += 64)
        G[i >> 6][i & 63] = gram[(size_t)s * 4096 + i];
    sqs[b] = sq[(size_t)b * S_ + s];
    __syncthreads();

    const float sqb = sqs[b];
    float dmin = INFINITY, dsum = 0.f;
    for (int c = 0; c < 64; ++c) {
        float d = sqb + sqs[c] - 2.0f * G[b][c];
        dmin = fminf(dmin, d);
        dsum = dsum + d;
    }
    float Z = 0.f;
    for (int c = 0; c < 64; ++c) {
        float d = sqb + sqs[c] - 2.0f * G[b][c];
        float e = expf(dmin - d);
        G[b][c] = e;
        Z = Z + e;
    }
    for (int c = 0; c < 64; ++c) G[b][c] = G[b][c] / Z;

    int knn[16];
    #pragma unroll
    for (int j = 0; j < 16; ++j) {
        float bp = -1.f; int bi2 = 0;
        for (int c = 0; c < 64; ++c) {
            float pv = G[b][c];
            if (pv > bp) { bp = pv; bi2 = c; }
        }
        knn[j] = bi2;
        G[b][bi2] = -1.f;
    }
    int cmatch = 0;
    #pragma unroll
    for (int j = 0; j < 16; ++j) cmatch += (knn[j] == j) ? 1 : 0;
    int lab[16];
    #pragma unroll
    for (int j = 0; j < 16; ++j) lab[j] = y[knn[j] * S_ + s];
    int bestc = -1, bestcls = 0;
    #pragma unroll
    for (int cls = 0; cls < 16; ++cls) {
        int cc = 0;
        #pragma unroll
        for (int j = 0; j < 16; ++j) cc += (lab[j] == cls) ? 1 : 0;
        if (cc > bestc) { bestc = cc; bestcls = cls; }
    }
    const int oi = s * 64 + b;
    contrib[oi] = dsum * (float)cmatch;
    assigned[oi] = bestcls;
    out_assigned_f[oi] = (float)bestcls;
}

__global__ __launch_bounds__(256)
void finalize_kernel(const float* __restrict__ contrib, const int* __restrict__ assigned,
                     const int* __restrict__ y, float* __restrict__ dout)
{
#pragma clang fp contract(off)
    __shared__ int cm[256];
    __shared__ float red[256];
    const int tid = threadIdx.x;
    cm[tid] = 0;
    float s = 0.f;
    for (int i = tid; i < NTOK; i += 256) s = s + contrib[i];
    red[tid] = s;
    __syncthreads();
    for (int i = tid; i < NTOK; i += 256)
        atomicAdd(&cm[assigned[i] * 16 + y[i]], 1);
    __syncthreads();
    for (int st = 128; st > 0; st >>= 1) {
        if (tid < st) red[tid] = red[tid] + red[tid + st];
        __syncthreads();
    }
    if (tid == 0) {
        dout[0] = red[0];
        float sij = 0.f, sa = 0.f, sb = 0.f;
        for (int i = 0; i < 256; ++i) {
            float mm = (float)cm[i];
            sij = sij + mm * (mm - 1.0f) * 0.5f;
        }
        for (int r = 0; r < 16; ++r) {
            int rs = 0;
            for (int c2 = 0; c2 < 16; ++c2) rs += cm[r * 16 + c2];
            float mm = (float)rs;
            sa = sa + mm * (mm - 1.0f) * 0.5f;
        }
        for (int c2 = 0; c2 < 16; ++c2) {
            int cs = 0;
            for (int r = 0; r < 16; ++r) cs += cm[r * 16 + c2];
            float mm = (float)cs;
            sb = sb + mm * (mm - 1.0f) * 0.5f;
        }
        float n = 16384.0f;
        float expv = sa * sb / (n * (n - 1.0f) * 0.5f);
        float mx = 0.5f * (sa + sb);
        dout[1] = (sij - expv) / (mx - expv);
    }
}

// ---------------------------------------------------------------------------
extern "C" void kernel_launch(void* const* d_in, const int* in_sizes, int n_in,
                              void* d_out, int out_size, void* d_ws, size_t ws_size,
                              hipStream_t stream)
{
    (void)in_sizes; (void)n_in; (void)out_size; (void)ws_size;
    const float* x     = (const float*)d_in[0];
    const float* W_emb = (const float*)d_in[1];
    const float* b_emb = (const float*)d_in[2];
    const float* Wq    = (const float*)d_in[3];
    const float* bq    = (const float*)d_in[4];
    const float* Wk    = (const float*)d_in[5];
    const float* bk    = (const float*)d_in[6];
    const float* Wv    = (const float*)d_in[7];
    const float* bv    = (const float*)d_in[8];
    const float* Wo    = (const float*)d_in[9];
    const float* bo    = (const float*)d_in[10];
    const float* ln1_s = (const float*)d_in[11];
    const float* ln1_b = (const float*)d_in[12];
    const float* W1    = (const float*)d_in[13];
    const float* b1    = (const float*)d_in[14];
    const float* W2    = (const float*)d_in[15];
    const float* b2    = (const float*)d_in[16];
    const float* ln2_s = (const float*)d_in[17];
    const float* ln2_b = (const float*)d_in[18];
    const float* e1_w  = (const float*)d_in[19];
    const float* e1_b  = (const float*)d_in[20];
    const float* e2_w  = (const float*)d_in[21];
    const float* e2_b  = (const float*)d_in[22];
    const float* d1_w  = (const float*)d_in[23];
    const float* d1_b  = (const float*)d_in[24];
    const float* d2_w  = (const float*)d_in[25];
    const float* d2_b  = (const float*)d_in[26];
    const int*   y     = (const int*)d_in[27];

    float* ws = (float*)d_ws;
    float*  h    = ws;                                   // 8388608
    ushort* hhi  = (ushort*)(ws + 8388608);
    ushort* hlo  = (ushort*)(ws + 12582912);
    float*  SCR  = ws + 16777216;                        // 20971520 slots scratch
    ushort* obhi = (ushort*)(ws + 37748736);
    ushort* oblo = (ushort*)(ws + 41943040);
    float*  wt   = ws + 46137344;
    ushort* WTQKV_HI = (ushort*)wt;
    ushort* WTQKV_LO = WTQKV_HI + 786432;
    ushort* WTO_HI   = WTQKV_LO + 786432;
    ushort* WTO_LO   = WTO_HI + 262144;
    ushort* WT1_HI   = WTO_LO + 262144;
    ushort* WT1_LO   = WT1_HI + 1048576;
    ushort* WT2_HI   = WT1_LO + 1048576;
    ushort* WT2_LO   = WT2_HI + 1048576;
    ushort* WE1_HI   = WT2_LO + 1048576;
    ushort* WE1_LO   = WE1_HI + 65536;
    ushort* WE2_HI   = WE1_LO + 65536;
    ushort* WE2_LO   = WE2_HI + 65536;
    ushort* WD1_HI   = WE2_LO + 65536;
    ushort* WD1_LO   = WD1_HI + 65536;
    ushort* WD2_HI   = WD1_LO + 65536;
    ushort* WD2_LO   = WD2_HI + 65536;
    float*  biasqkv  = ws + 49545216;

    // attention-phase overlays
    ushort* Phi_  = (ushort*)SCR;                        // [0 .. 4.2M slots)
    ushort* Plo_  = (ushort*)(SCR + 4194304);            // [.. 8.4M)
    ushort* qkvhi = (ushort*)(SCR + 8388608);            // [.. 11.5M)
    ushort* qkvlo = (ushort*)(SCR + 11534336);           // [.. 14.7M)
    ushort* VThi  = (ushort*)(SCR + 14680064);           // [.. 15.7M)
    ushort* VTlo  = (ushort*)(SCR + 15728640);           // [.. 16.8M)
    // post-attention / FFN phase:
    float*  Of32  = SCR;
    ushort* f1hi  = (ushort*)SCR;
    ushort* f1lo  = (ushort*)(SCR + 8388608);
    float*  Xhalf = SCR + 16777216;
    // cluster phase:
    ushort* enchi = (ushort*)SCR;
    ushort* enclo = (ushort*)(SCR + 4194304);
    float*  z     = SCR + 8388608;
    float*  gram  = SCR + 16777216;
    float*  sqb_  = SCR + 17825792;
    float*  contrib = SCR + 17842176;
    int*    assigned = (int*)(SCR + 17858560);
    ushort* t1hi = obhi;
    ushort* t1lo = oblo;
    ushort* t2hi = obhi + 2097152;
    ushort* t2lo = oblo + 2097152;
    float*  dout = (float*)d_out;

    dim3 blk(256);
    auto gg = [](int M, int N) { return dim3(N >> 7, M >> 7); };

    transpose_split<<<dim3(2, 8), blk, 0, stream>>>(e1_w, WE1_HI, WE1_LO, 512, 128);
    transpose_split<<<dim3(8, 2), blk, 0, stream>>>(e2_w, WE2_HI, WE2_LO, 128, 512);
    transpose_split<<<dim3(2, 8), blk, 0, stream>>>(d1_w, WD1_HI, WD1_LO, 512, 128);
    transpose_split<<<dim3(8, 2), blk, 0, stream>>>(d2_w, WD2_HI, WD2_LO, 128, 512);

    gemm_f32<<<dim3(8, 256), blk, 0, stream>>>(x, W_emb, b_emb, h, hhi, hlo, NTOK, D_, IN_);

    for (int l = 0; l < L_; ++l) {
        prep_layer<<<dim3(774), blk, 0, stream>>>(
            Wq + (size_t)l*D_*D_, Wk + (size_t)l*D_*D_, Wv + (size_t)l*D_*D_,
            Wo + (size_t)l*D_*D_, W1 + (size_t)l*D_*DFF_, W2 + (size_t)l*DFF_*D_,
            bq + l*D_, bk + l*D_, bv + l*D_,
            WTQKV_HI, WTQKV_LO, WTO_HI, WTO_LO, WT1_HI, WT1_LO, WT2_HI, WT2_LO,
            biasqkv);

        for (int qtr = 0; qtr < 4; ++qtr) {
            const size_t hoff = (size_t)qtr * 4096 * 512;
            gemm3<2><<<gg(4096, 1536), blk, 0, stream>>>(
                hhi + hoff, hlo + hoff, WTQKV_HI, WTQKV_LO, biasqkv,
                nullptr, qkvhi, qkvlo, 4096, 1536, 512);
            qks_gemm<<<dim3(2, 128), blk, 0, stream>>>(qkvhi, qkvlo, Phi_, Plo_,
                                                       VThi, VTlo);
            pv_gemm<<<dim3(2, 128), blk, 0, stream>>>(Phi_, Plo_, VThi, VTlo,
                                                      obhi, oblo, qtr * 4096);
        }
        gemm3<0><<<gg(NTOK, 512), blk, 0, stream>>>(
            obhi, oblo, WTO_HI, WTO_LO, bo + l*D_,
            Of32, nullptr, nullptr, NTOK, 512, 512);
        ln_res<<<dim3(NTOK / 4), blk, 0, stream>>>(h, Of32, ln1_s + l*D_, ln1_b + l*D_, hhi, hlo);

        for (int half = 0; half < 2; ++half) {
            const size_t ro = (size_t)half * HALF_ * D_;
            gemm3<3><<<gg(HALF_, DFF_), blk, 0, stream>>>(
                hhi + ro, hlo + ro, WT1_HI, WT1_LO, b1 + l*DFF_,
                nullptr, f1hi, f1lo, HALF_, 2048, 512);
            gemm3<0><<<gg(HALF_, 512), blk, 0, stream>>>(
                f1hi, f1lo, WT2_HI, WT2_LO, b2 + l*D_,
                Xhalf, nullptr, nullptr, HALF_, 512, 2048);
            ln_res<<<dim3(HALF_ / 4), blk, 0, stream>>>(
                h + ro, Xhalf, ln2_s + l*D_, ln2_b + l*D_, hhi + ro, hlo + ro);
        }
    }

    gemm3<3><<<gg(NTOK, 128), blk, 0, stream>>>(
        hhi, hlo, WE1_HI, WE1_LO, e1_b, nullptr, t1hi, t1lo, NTOK, 128, 512);
    gemm3<2><<<gg(NTOK, 512), blk, 0, stream>>>(
        t1hi, t1lo, WE2_HI, WE2_LO, e2_b, nullptr, enchi, enclo, NTOK, 512, 128);
    gemm3<3><<<gg(NTOK, 128), blk, 0, stream>>>(
        enchi, enclo, WD1_HI, WD1_LO, d1_b, nullptr, t2hi, t2lo, NTOK, 128, 512);
    gemm3<0><<<gg(NTOK, 512), blk, 0, stream>>>(
        t2hi, t2lo, WD2_HI, WD2_LO, d2_b, z, nullptr, nullptr, NTOK, 512, 128);

    zout_sq<<<dim3(NTOK / 4), blk, 0, stream>>>(z, dout + 16386, sqb_);
    gram_kernel<<<dim3(S_), blk, 0, stream>>>(z, gram);
    cluster_kernel<<<dim3(S_), dim3(64), 0, stream>>>(gram, sqb_, y, contrib, assigned, dout + 2);
    finalize_kernel<<<dim3(1), blk, 0, stream>>>(contrib, assigned, y, dout);
}

// Round 12
// 1438.675 us; speedup vs baseline: 1.1651x; 1.0014x over previous
//
#include <hip/hip_runtime.h>
#include <cstdint>
#include <cmath>

#define B_ 64
#define S_ 256
#define IN_ 32
#define D_ 512
#define H_ 8
#define L_ 2
#define DFF_ 2048
#define C_ 16
#define DH_ 64
#define NTOK (B_*S_)   // 16384
#define HALF_ 8192

typedef __attribute__((ext_vector_type(8))) short bf16x8;
typedef __attribute__((ext_vector_type(4))) float f32x4;
typedef __attribute__((ext_vector_type(8))) ushort ushortx8;

__device__ __forceinline__ ushort bf16_rn(float x) {
    union { float f; uint32_t u; } v; v.f = x;
    uint32_t r = v.u + 0x7fffu + ((v.u >> 16) & 1u);
    return (ushort)(r >> 16);
}
__device__ __forceinline__ float bf16_f32(ushort h) {
    union { uint32_t u; float f; } v; v.u = ((uint32_t)h) << 16;
    return v.f;
}

#define GLDS(gp, lp) __builtin_amdgcn_global_load_lds( \
    (const __attribute__((address_space(1))) void*)(gp), \
    (__attribute__((address_space(3))) void*)(lp), 16, 0, 0)

// XCD-chunk bijective swizzle (nwg % 8 == 0 for all users).
__device__ __forceinline__ int xcd_swz(int lid, int nwg) {
    return (lid & 7) * (nwg >> 3) + (lid >> 3);
}

// ---------------------------------------------------------------------------
// Merged bf16x3 GEMM (128x128, 2-phase, counted vmcnt). All 4 operand streams
// staged once per K-tile (48 MFMA : 16 ds_read_b128), 64 KB LDS dbuf.
// XCD mapping: contiguous M-chunk per XCD, N split into groups of GN so the
// concurrent L2 working set (A panels + B panels) stays <= 4 MB.
// MODE: 0 = f32 out, 2 = split hi/lo out, 3 = split + ReLU.
// ---------------------------------------------------------------------------
template<int MODE>
__global__ __launch_bounds__(256)
void gemm3(const ushort* __restrict__ Ahi, const ushort* __restrict__ Alo,
           const ushort* __restrict__ Bhi, const ushort* __restrict__ Blo,
           const float* __restrict__ bias,
           float* __restrict__ Cf, ushort* __restrict__ Chi, ushort* __restrict__ Clo,
           int M, int N, int K)
{
    __shared__ __align__(16) ushort Als[2][2][128*32];
    __shared__ __align__(16) ushort Bls[2][2][128*32];
    const int tid  = threadIdx.x;
    const int wave = tid >> 6, lane = tid & 63;
    const int gx = gridDim.x;
    const int nwg = gx * gridDim.y;
    const int lid = blockIdx.y * gx + blockIdx.x;
    const int xcd = lid & 7, l = lid >> 3;
    const int nl  = nwg >> 3;
    const int GN  = (gx <= 8) ? gx : ((gx == 16) ? 8 : 6);
    const int cm  = nl / gx;
    const int seg = l / (cm * GN);
    const int r   = l - seg * (cm * GN);
    const int m0 = (xcd * cm + r / GN) << 7;
    const int n0 = (seg * GN + r % GN) << 7;
    const int wr = wave >> 1, wc = wave & 1;

    const ushort* Ah = Ahi + (size_t)m0 * K;
    const ushort* Al = Alo + (size_t)m0 * K;
    const ushort* Bh = Bhi + (size_t)n0 * K;
    const ushort* Bl = Blo + (size_t)n0 * K;

    const int KT = K >> 5;

    f32x4 acc[4][4];
    #pragma unroll
    for (int m = 0; m < 4; ++m)
        #pragma unroll
        for (int n = 0; n < 4; ++n)
            acc[m][n] = (f32x4){0.f, 0.f, 0.f, 0.f};

    auto stage = [&](int buf, int kk) {
        #pragma unroll
        for (int i = 0; i < 2; ++i) {
            const int rbase = wave * 32 + i * 16;
            const int row   = rbase + (lane >> 2);
            const int slot  = (lane & 3) ^ ((row >> 1) & 3);
            GLDS(Ah + (size_t)row * K + kk + slot * 8, &Als[buf][0][rbase * 32]);
            GLDS(Al + (size_t)row * K + kk + slot * 8, &Als[buf][1][rbase * 32]);
            GLDS(Bh + (size_t)row * K + kk + slot * 8, &Bls[buf][0][rbase * 32]);
            GLDS(Bl + (size_t)row * K + kk + slot * 8, &Bls[buf][1][rbase * 32]);
        }
    };

    stage(0, 0);
    for (int t = 0; t < KT; ++t) {
        const int buf = t & 1;
        if (t + 1 < KT) {
            stage(buf ^ 1, (t + 1) << 5);
            asm volatile("s_waitcnt vmcnt(8)" ::: "memory");
        } else {
            asm volatile("s_waitcnt vmcnt(0)" ::: "memory");
        }
        __builtin_amdgcn_sched_barrier(0);
        __builtin_amdgcn_s_barrier();

        const int chunk = lane >> 4;
        bf16x8 afh[4], afl[4], bfh[4], bfl[4];
        #pragma unroll
        for (int m = 0; m < 4; ++m) {
            const int row = wr * 64 + m * 16 + (lane & 15);
            const int sl  = chunk ^ ((row >> 1) & 3);
            afh[m] = *(const bf16x8*)(&Als[buf][0][row * 32 + sl * 8]);
            afl[m] = *(const bf16x8*)(&Als[buf][1][row * 32 + sl * 8]);
        }
        #pragma unroll
        for (int n = 0; n < 4; ++n) {
            const int row = wc * 64 + n * 16 + (lane & 15);
            const int sl  = chunk ^ ((row >> 1) & 3);
            bfh[n] = *(const bf16x8*)(&Bls[buf][0][row * 32 + sl * 8]);
            bfl[n] = *(const bf16x8*)(&Bls[buf][1][row * 32 + sl * 8]);
        }
        #pragma unroll
        for (int m = 0; m < 4; ++m)
            #pragma unroll
            for (int n = 0; n < 4; ++n) {
                acc[m][n] = __builtin_amdgcn_mfma_f32_16x16x32_bf16(afh[m], bfh[n], acc[m][n], 0, 0, 0);
                acc[m][n] = __builtin_amdgcn_mfma_f32_16x16x32_bf16(afh[m], bfl[n], acc[m][n], 0, 0, 0);
                acc[m][n] = __builtin_amdgcn_mfma_f32_16x16x32_bf16(afl[m], bfh[n], acc[m][n], 0, 0, 0);
            }
        __builtin_amdgcn_sched_barrier(0);
        __builtin_amdgcn_s_barrier();
    }

    const int col_l = lane & 15;
    float bv[4];
    #pragma unroll
    for (int n = 0; n < 4; ++n) bv[n] = bias[n0 + wc * 64 + n * 16 + col_l];
    #pragma unroll
    for (int m = 0; m < 4; ++m) {
        #pragma unroll
        for (int j = 0; j < 4; ++j) {
            const size_t grow = (size_t)(m0 + wr * 64 + m * 16 + (lane >> 4) * 4 + j);
            #pragma unroll
            for (int n = 0; n < 4; ++n) {
                float x = acc[m][n][j] + bv[n];
                if (MODE & 1) x = fmaxf(x, 0.f);
                const size_t gidx = grow * N + (n0 + wc * 64 + n * 16 + col_l);
                if (MODE < 2) {
                    Cf[gidx] = x;
                } else {
                    ushort hb = bf16_rn(x);
                    Chi[gidx] = hb;
                    Clo[gidx] = bf16_rn(x - bf16_f32(hb));
                }
            }
        }
    }
}

// ---------------------------------------------------------------------------
// Dedicated N=128, K=512 bf16x3 GEMM with ReLU+split output (e1/d1 heads).
// Tile 64(M) x 128(N), 4 waves = 4 N-quadrants (wave tile 64x32), 48 KB LDS
// (3 blocks/CU), grid = M/64 = 256 blocks (full fill vs 128 at 128-tile).
// Same per-element MFMA order as gemm3 -> bit-identical results.
// ---------------------------------------------------------------------------
__global__ __launch_bounds__(256)
void gemm3_n128(const ushort* __restrict__ Ahi, const ushort* __restrict__ Alo,
                const ushort* __restrict__ Bhi, const ushort* __restrict__ Blo,
                const float* __restrict__ bias,
                ushort* __restrict__ Chi, ushort* __restrict__ Clo, int M)
{
    __shared__ __align__(16) ushort Als[2][2][64*32];
    __shared__ __align__(16) ushort Bls[2][2][128*32];
    const int tid = threadIdx.x, wave = tid >> 6, lane = tid & 63;
    const int m0 = xcd_swz(blockIdx.x, gridDim.x) << 6;
    const int K = 512, N = 128;

    const ushort* Ah = Ahi + (size_t)m0 * K;
    const ushort* Al = Alo + (size_t)m0 * K;

    f32x4 acc[4][2];
    #pragma unroll
    for (int m = 0; m < 4; ++m)
        #pragma unroll
        for (int n = 0; n < 2; ++n)
            acc[m][n] = (f32x4){0.f, 0.f, 0.f, 0.f};

    // per wave per tile: A 1 GLDS (16 rows) x2 streams + B 2 GLDS x2 = 6 insts
    auto stage = [&](int buf, int kk) {
        {
            const int rbase = wave * 16;
            const int row   = rbase + (lane >> 2);
            const int slot  = (lane & 3) ^ ((row >> 1) & 3);
            GLDS(Ah + (size_t)row * K + kk + slot * 8, &Als[buf][0][rbase * 32]);
            GLDS(Al + (size_t)row * K + kk + slot * 8, &Als[buf][1][rbase * 32]);
        }
        #pragma unroll
        for (int i = 0; i < 2; ++i) {
            const int rbase = wave * 32 + i * 16;
            const int row   = rbase + (lane >> 2);
            const int slot  = (lane & 3) ^ ((row >> 1) & 3);
            GLDS(Bhi + (size_t)row * K + kk + slot * 8, &Bls[buf][0][rbase * 32]);
            GLDS(Blo + (size_t)row * K + kk + slot * 8, &Bls[buf][1][rbase * 32]);
        }
    };

    stage(0, 0);
    for (int t = 0; t < 16; ++t) {
        const int buf = t & 1;
        if (t + 1 < 16) {
            stage(buf ^ 1, (t + 1) << 5);
            asm volatile("s_waitcnt vmcnt(6)" ::: "memory");
        } else {
            asm volatile("s_waitcnt vmcnt(0)" ::: "memory");
        }
        __builtin_amdgcn_sched_barrier(0);
        __builtin_amdgcn_s_barrier();

        const int chunk = lane >> 4;
        bf16x8 afh[4], afl[4], bfh[2], bfl[2];
        #pragma unroll
        for (int m = 0; m < 4; ++m) {
            const int row = m * 16 + (lane & 15);
            const int sl  = chunk ^ ((row >> 1) & 3);
            afh[m] = *(const bf16x8*)(&Als[buf][0][row * 32 + sl * 8]);
            afl[m] = *(const bf16x8*)(&Als[buf][1][row * 32 + sl * 8]);
        }
        #pragma unroll
        for (int n = 0; n < 2; ++n) {
            const int row = wave * 32 + n * 16 + (lane & 15);
            const int sl  = chunk ^ ((row >> 1) & 3);
            bfh[n] = *(const bf16x8*)(&Bls[buf][0][row * 32 + sl * 8]);
            bfl[n] = *(const bf16x8*)(&Bls[buf][1][row * 32 + sl * 8]);
        }
        #pragma unroll
        for (int m = 0; m < 4; ++m)
            #pragma unroll
            for (int n = 0; n < 2; ++n) {
                acc[m][n] = __builtin_amdgcn_mfma_f32_16x16x32_bf16(afh[m], bfh[n], acc[m][n], 0, 0, 0);
                acc[m][n] = __builtin_amdgcn_mfma_f32_16x16x32_bf16(afh[m], bfl[n], acc[m][n], 0, 0, 0);
                acc[m][n] = __builtin_amdgcn_mfma_f32_16x16x32_bf16(afl[m], bfh[n], acc[m][n], 0, 0, 0);
            }
        __builtin_amdgcn_sched_barrier(0);
        __builtin_amdgcn_s_barrier();
    }

    const int col_l = lane & 15;
    float bv[2];
    #pragma unroll
    for (int n = 0; n < 2; ++n) bv[n] = bias[wave * 32 + n * 16 + col_l];
    #pragma unroll
    for (int m = 0; m < 4; ++m) {
        #pragma unroll
        for (int j = 0; j < 4; ++j) {
            const size_t grow = (size_t)(m0 + m * 16 + (lane >> 4) * 4 + j);
            #pragma unroll
            for (int n = 0; n < 2; ++n) {
                float x = fmaxf(acc[m][n][j] + bv[n], 0.f);
                const size_t gidx = grow * N + (wave * 32 + n * 16 + col_l);
                ushort hb = bf16_rn(x);
                Chi[gidx] = hb;
                Clo[gidx] = bf16_rn(x - bf16_f32(hb));
            }
        }
    }
}

// ---------------------------------------------------------------------------
// Fused QK^T + row-softmax (bf16x3) + V-transpose epilogue.
// ---------------------------------------------------------------------------
__global__ __launch_bounds__(256)
void qks_gemm(const ushort* __restrict__ qkvhi, const ushort* __restrict__ qkvlo,
              ushort* __restrict__ Phi, ushort* __restrict__ Plo,
              ushort* __restrict__ VThi, ushort* __restrict__ VTlo)
{
    __shared__ __align__(16) ushort Qls[2][128*64];   // [hi/lo][row*64]
    __shared__ __align__(16) ushort Kls[2][128*64];
    const int tid = threadIdx.x, wave = tid >> 6, lane = tid & 63;
    const int swz = xcd_swz(blockIdx.y * 2 + blockIdx.x, 256);
    const int bh = swz >> 1, qt = swz & 1;
    const int b = bh >> 3, h = bh & 7;

    const ushort* Qh = qkvhi + ((size_t)(b * 256 + qt * 128)) * 1536 + h * 64;
    const ushort* Ql = qkvlo + ((size_t)(b * 256 + qt * 128)) * 1536 + h * 64;
    const ushort* Kh = qkvhi + ((size_t)(b * 256)) * 1536 + 512 + h * 64;
    const ushort* Kl = qkvlo + ((size_t)(b * 256)) * 1536 + 512 + h * 64;

    auto stage128 = [&](const ushort* src, ushort* dst) {
        #pragma unroll
        for (int j = 0; j < 4; ++j) {
            const int rl   = j * 32 + wave * 8 + (lane >> 3);
            const int slot = (lane & 7) ^ (rl & 7);
            GLDS(src + (size_t)rl * 1536 + slot * 8, dst + (j * 32 + wave * 8) * 64);
        }
    };

    f32x4 acc[2][16];
    #pragma unroll
    for (int mi = 0; mi < 2; ++mi)
        #pragma unroll
        for (int nj = 0; nj < 16; ++nj)
            acc[mi][nj] = (f32x4){0.f, 0.f, 0.f, 0.f};

    stage128(Qh, &Qls[0][0]);
    stage128(Ql, &Qls[1][0]);
    stage128(Kh, &Kls[0][0]);
    stage128(Kl, &Kls[1][0]);
    asm volatile("s_waitcnt vmcnt(0)" ::: "memory");
    __builtin_amdgcn_sched_barrier(0);
    __builtin_amdgcn_s_barrier();

    bf16x8 qh[2][2], ql[2][2];
    #pragma unroll
    for (int mi = 0; mi < 2; ++mi)
        #pragma unroll
        for (int ks = 0; ks < 2; ++ks) {
            const int row = wave * 32 + mi * 16 + (lane & 15);
            const int es  = (ks * 4 + (lane >> 4)) ^ (lane & 7);
            qh[mi][ks] = *(const bf16x8*)&Qls[0][row * 64 + es * 8];
            ql[mi][ks] = *(const bf16x8*)&Qls[1][row * 64 + es * 8];
        }

    #pragma unroll
    for (int hk = 0; hk < 2; ++hk) {
        if (hk == 1) {
            __syncthreads();
            stage128(Kh + (size_t)128 * 1536, &Kls[0][0]);
            stage128(Kl + (size_t)128 * 1536, &Kls[1][0]);
            asm volatile("s_waitcnt vmcnt(0)" ::: "memory");
            __builtin_amdgcn_sched_barrier(0);
            __builtin_amdgcn_s_barrier();
        }
        #pragma unroll
        for (int ng = 0; ng < 2; ++ng) {
            bf16x8 kh[4][2], kl[4][2];
            #pragma unroll
            for (int nj = 0; nj < 4; ++nj)
                #pragma unroll
                for (int ks = 0; ks < 2; ++ks) {
                    const int row = (ng * 4 + nj) * 16 + (lane & 15);
                    const int es  = (ks * 4 + (lane >> 4)) ^ (lane & 7);
                    kh[nj][ks] = *(const bf16x8*)&Kls[0][row * 64 + es * 8];
                    kl[nj][ks] = *(const bf16x8*)&Kls[1][row * 64 + es * 8];
                }
            #pragma unroll
            for (int mi = 0; mi < 2; ++mi)
                #pragma unroll
                for (int nj = 0; nj < 4; ++nj) {
                    const int an = hk * 8 + ng * 4 + nj;
                    #pragma unroll
                    for (int ks = 0; ks < 2; ++ks) {
                        acc[mi][an] = __builtin_amdgcn_mfma_f32_16x16x32_bf16(qh[mi][ks], kh[nj][ks], acc[mi][an], 0, 0, 0);
                        acc[mi][an] = __builtin_amdgcn_mfma_f32_16x16x32_bf16(qh[mi][ks], kl[nj][ks], acc[mi][an], 0, 0, 0);
                        acc[mi][an] = __builtin_amdgcn_mfma_f32_16x16x32_bf16(ql[mi][ks], kh[nj][ks], acc[mi][an], 0, 0, 0);
                    }
                }
        }
    }

    const int colb = lane & 15;
    #pragma unroll
    for (int mi = 0; mi < 2; ++mi) {
        #pragma unroll
        for (int j = 0; j < 4; ++j) {
            float v[16];
            float mx = -INFINITY;
            #pragma unroll
            for (int nj = 0; nj < 16; ++nj) {
                v[nj] = acc[mi][nj][j] * 0.125f;
                mx = fmaxf(mx, v[nj]);
            }
            #pragma unroll
            for (int d = 1; d < 16; d <<= 1) mx = fmaxf(mx, __shfl_xor(mx, d));
            float sum = 0.f;
            #pragma unroll
            for (int nj = 0; nj < 16; ++nj) {
                v[nj] = expf(v[nj] - mx);
                sum += v[nj];
            }
            #pragma unroll
            for (int d = 1; d < 16; d <<= 1) sum += __shfl_xor(sum, d);
            const float inv = 1.0f / sum;
            const int qrow = qt * 128 + wave * 32 + mi * 16 + (lane >> 4) * 4 + j;
            const size_t base = ((size_t)bh * 256 + qrow) * 256;
            #pragma unroll
            for (int nj = 0; nj < 16; ++nj) {
                float p = v[nj] * inv;
                ushort hb = bf16_rn(p);
                Phi[base + nj * 16 + colb] = hb;
                Plo[base + nj * 16 + colb] = bf16_rn(p - bf16_f32(hb));
            }
        }
    }

    // fused V-transpose: rows [qt*128, +128) of this bh -> VT
    {
        ushort* T = &Qls[0][0];            // 64*144 = 9216 ushorts
        const int TP = 144;
        const ushort* vsrcs[2] = {
            qkvhi + ((size_t)(b * 256 + qt * 128)) * 1536 + 1024 + h * 64,
            qkvlo + ((size_t)(b * 256 + qt * 128)) * 1536 + 1024 + h * 64 };
        ushort* vdsts[2] = { VThi, VTlo };
        #pragma unroll
        for (int pass = 0; pass < 2; ++pass) {
            __syncthreads();
            if (tid < 128) {
                const ushort* p = vsrcs[pass] + (size_t)tid * 1536;
                #pragma unroll
                for (int i = 0; i < 8; ++i) {
                    ushortx8 vv = *(const ushortx8*)(p + i * 8);
                    #pragma unroll
                    for (int j = 0; j < 8; ++j) T[(i * 8 + j) * TP + tid] = vv[j];
                }
            }
            __syncthreads();
            {
                const int dh = tid >> 2;
                const int kseg = (tid & 3) * 32;
                ushort* op = vdsts[pass] + ((size_t)bh * 64 + dh) * 256 + qt * 128 + kseg;
                #pragma unroll
                for (int i = 0; i < 4; ++i) {
                    ushortx8 vv;
                    #pragma unroll
                    for (int j = 0; j < 8; ++j) vv[j] = T[dh * TP + kseg + i * 8 + j];
                    *(ushortx8*)(op + i * 8) = vv;
                }
            }
        }
    }
}

// ---------------------------------------------------------------------------
// Batched PV: O[q][dh] = P[q][:] . V[:, dh] (bf16x3), O written split hi/lo.
// ---------------------------------------------------------------------------
__global__ __launch_bounds__(256)
void pv_gemm(const ushort* __restrict__ Phi, const ushort* __restrict__ Plo,
             const ushort* __restrict__ VThi, const ushort* __restrict__ VTlo,
             ushort* __restrict__ obhi, ushort* __restrict__ oblo, int t0)
{
    __shared__ __align__(16) ushort Als[2][2][128*32];
    __shared__ __align__(16) ushort Bls[2][2][64*32];
    const int tid = threadIdx.x, wave = tid >> 6, lane = tid & 63;
    const int swz = xcd_swz(blockIdx.y * 2 + blockIdx.x, 256);
    const int bh = swz >> 1, qt = swz & 1;
    const ushort* Ah = Phi + ((size_t)bh * 256 + qt * 128) * 256;
    const ushort* Al = Plo + ((size_t)bh * 256 + qt * 128) * 256;
    const ushort* Bh = VThi + (size_t)bh * 64 * 256;
    const ushort* Bl = VTlo + (size_t)bh * 64 * 256;

    f32x4 acc[2][4];
    #pragma unroll
    for (int m = 0; m < 2; ++m)
        #pragma unroll
        for (int n = 0; n < 4; ++n)
            acc[m][n] = (f32x4){0.f, 0.f, 0.f, 0.f};

    auto stage = [&](int buf, int kk) {
        #pragma unroll
        for (int i = 0; i < 2; ++i) {
            const int rbase = wave * 32 + i * 16;
            const int row   = rbase + (lane >> 2);
            const int slot  = (lane & 3) ^ ((row >> 1) & 3);
            GLDS(Ah + (size_t)row * 256 + kk + slot * 8, &Als[buf][0][rbase * 32]);
            GLDS(Al + (size_t)row * 256 + kk + slot * 8, &Als[buf][1][rbase * 32]);
        }
        const int rbase2 = wave * 16;
        const int row2   = rbase2 + (lane >> 2);
        const int slot2  = (lane & 3) ^ ((row2 >> 1) & 3);
        GLDS(Bh + (size_t)row2 * 256 + kk + slot2 * 8, &Bls[buf][0][rbase2 * 32]);
        GLDS(Bl + (size_t)row2 * 256 + kk + slot2 * 8, &Bls[buf][1][rbase2 * 32]);
    };

    stage(0, 0);
    for (int t = 0; t < 8; ++t) {
        const int buf = t & 1;
        __syncthreads();
        if (t < 7) stage(buf ^ 1, (t + 1) << 5);
        const int chunk = lane >> 4;
        bf16x8 afh[2], afl[2], bfh[4], bfl[4];
        #pragma unroll
        for (int m = 0; m < 2; ++m) {
            const int row = wave * 32 + m * 16 + (lane & 15);
            const int sl  = chunk ^ ((row >> 1) & 3);
            afh[m] = *(const bf16x8*)(&Als[buf][0][row * 32 + sl * 8]);
            afl[m] = *(const bf16x8*)(&Als[buf][1][row * 32 + sl * 8]);
        }
        #pragma unroll
        for (int n = 0; n < 4; ++n) {
            const int row = n * 16 + (lane & 15);
            const int sl  = chunk ^ ((row >> 1) & 3);
            bfh[n] = *(const bf16x8*)(&Bls[buf][0][row * 32 + sl * 8]);
            bfl[n] = *(const bf16x8*)(&Bls[buf][1][row * 32 + sl * 8]);
        }
        #pragma unroll
        for (int m = 0; m < 2; ++m)
            #pragma unroll
            for (int n = 0; n < 4; ++n) {
                acc[m][n] = __builtin_amdgcn_mfma_f32_16x16x32_bf16(afh[m], bfh[n], acc[m][n], 0, 0, 0);
                acc[m][n] = __builtin_amdgcn_mfma_f32_16x16x32_bf16(afh[m], bfl[n], acc[m][n], 0, 0, 0);
                acc[m][n] = __builtin_amdgcn_mfma_f32_16x16x32_bf16(afl[m], bfh[n], acc[m][n], 0, 0, 0);
            }
        __syncthreads();
    }

    const int b = bh >> 3, h = bh & 7;
    const int col_l = lane & 15;
    #pragma unroll
    for (int m = 0; m < 2; ++m)
        #pragma unroll
        for (int j = 0; j < 4; ++j) {
            const int q = qt * 128 + wave * 32 + m * 16 + (lane >> 4) * 4 + j;
            const size_t token = (size_t)t0 + (size_t)b * 256 + q;
            #pragma unroll
            for (int n = 0; n < 4; ++n) {
                const int col = h * 64 + n * 16 + col_l;
                float x = acc[m][n][j];
                ushort hb = bf16_rn(x);
                obhi[token * 512 + col] = hb;
                oblo[token * 512 + col] = bf16_rn(x - bf16_f32(hb));
            }
        }
}

// ---------------------------------------------------------------------------
// f32 GEMM (embedding only, K=32) with fused bf16 hi/lo split output.
// ---------------------------------------------------------------------------
__global__ __launch_bounds__(256)
void gemm_f32(const float* __restrict__ A, const float* __restrict__ W,
              const float* __restrict__ bias, float* __restrict__ Cc,
              ushort* __restrict__ Chi, ushort* __restrict__ Clo,
              int M, int N, int K)
{
    __shared__ float As[16][68];
    __shared__ float Bs[16][64];
    const int tid = threadIdx.x;
    const int tx = tid & 15, ty = tid >> 4;
    const int m0 = blockIdx.y << 6, n0 = blockIdx.x << 6;
    const int arow = tid >> 2, ak4 = (tid & 3) << 2;
    const int brow = tid >> 4, bc4 = (tid & 15) << 2;
    float acc[4][4] = {};
    const float* aptr = A + (size_t)(m0 + arow) * K + ak4;
    const float* bptr = W + (size_t)brow * N + n0 + bc4;
    for (int k0 = 0; k0 < K; k0 += 16) {
        float4 av = *(const float4*)(aptr + k0);
        float4 bv = *(const float4*)(bptr + (size_t)k0 * N);
        __syncthreads();
        As[ak4+0][arow] = av.x; As[ak4+1][arow] = av.y;
        As[ak4+2][arow] = av.z; As[ak4+3][arow] = av.w;
        *(float4*)&Bs[brow][bc4] = bv;
        __syncthreads();
        #pragma unroll
        for (int kk = 0; kk < 16; ++kk) {
            float4 a = *(const float4*)&As[kk][ty << 2];
            float4 b = *(const float4*)&Bs[kk][tx << 2];
            float ar[4] = {a.x,a.y,a.z,a.w};
            float br[4] = {b.x,b.y,b.z,b.w};
            #pragma unroll
            for (int i = 0; i < 4; ++i)
                #pragma unroll
                for (int j = 0; j < 4; ++j)
                    acc[i][j] = fmaf(ar[i], br[j], acc[i][j]);
        }
    }
    float4 bb = *(const float4*)(bias + n0 + (tx << 2));
    #pragma unroll
    for (int i = 0; i < 4; ++i) {
        int m = m0 + (ty << 2) + i;
        float o[4];
        o[0] = acc[i][0] + bb.x; o[1] = acc[i][1] + bb.y;
        o[2] = acc[i][2] + bb.z; o[3] = acc[i][3] + bb.w;
        ushort4 hh, ll;
        hh.x = bf16_rn(o[0]); ll.x = bf16_rn(o[0] - bf16_f32(hh.x));
        hh.y = bf16_rn(o[1]); ll.y = bf16_rn(o[1] - bf16_f32(hh.y));
        hh.z = bf16_rn(o[2]); ll.z = bf16_rn(o[2] - bf16_f32(hh.z));
        hh.w = bf16_rn(o[3]); ll.w = bf16_rn(o[3] - bf16_f32(hh.w));
        const size_t base = (size_t)m * N + n0 + (tx << 2);
        *(float4*)(Cc + base) = (float4){o[0],o[1],o[2],o[3]};
        *(ushort4*)(Chi + base) = hh;
        *(ushort4*)(Clo + base) = ll;
    }
}

// ---------------------------------------------------------------------------
// Per-layer weight prep: all 6 transposes + qkv-bias concat in ONE dispatch.
// ---------------------------------------------------------------------------
__global__ __launch_bounds__(256)
void prep_layer(const float* __restrict__ Wq, const float* __restrict__ Wk,
                const float* __restrict__ Wv, const float* __restrict__ Wo,
                const float* __restrict__ W1, const float* __restrict__ W2,
                const float* __restrict__ bq, const float* __restrict__ bk,
                const float* __restrict__ bv,
                ushort* __restrict__ WTQKV_HI, ushort* __restrict__ WTQKV_LO,
                ushort* __restrict__ WTO_HI, ushort* __restrict__ WTO_LO,
                ushort* __restrict__ WT1_HI, ushort* __restrict__ WT1_LO,
                ushort* __restrict__ WT2_HI, ushort* __restrict__ WT2_LO,
                float* __restrict__ biasqkv)
{
    __shared__ float T[64][65];
    const int blk = blockIdx.x;
    const int tid = threadIdx.x;
    if (blk >= 768) {
        int i = (blk - 768) * 256 + tid;
        biasqkv[i] = (i < 512) ? bq[i] : (i < 1024 ? bk[i - 512] : bv[i - 1024]);
        return;
    }
    const float* W; ushort* Thi; ushort* Tlo; int K, N, bx, by;
    if (blk < 192) {
        const int wsel = blk / 64, idx = blk % 64;
        W = (wsel == 0) ? Wq : ((wsel == 1) ? Wk : Wv);
        Thi = WTQKV_HI + (size_t)wsel * 512 * 512;
        Tlo = WTQKV_LO + (size_t)wsel * 512 * 512;
        K = 512; N = 512; bx = idx % 8; by = idx / 8;
    } else if (blk < 256) {
        const int idx = blk - 192;
        W = Wo; Thi = WTO_HI; Tlo = WTO_LO;
        K = 512; N = 512; bx = idx % 8; by = idx / 8;
    } else if (blk < 512) {
        const int idx = blk - 256;
        W = W1; Thi = WT1_HI; Tlo = WT1_LO;
        K = 512; N = 2048; bx = idx % 32; by = idx / 32;
    } else {
        const int idx = blk - 512;
        W = W2; Thi = WT2_HI; Tlo = WT2_LO;
        K = 2048; N = 512; bx = idx % 8; by = idx / 8;
    }
    const int k0 = by << 6, n0 = bx << 6;
    #pragma unroll
    for (int i = 0; i < 16; ++i) {
        int idx = tid + i * 256;
        int kl = idx >> 6, nl = idx & 63;
        T[nl][kl] = W[(size_t)(k0 + kl) * N + n0 + nl];
    }
    __syncthreads();
    #pragma unroll
    for (int i = 0; i < 16; ++i) {
        int idx = tid + i * 256;
        int nl = idx >> 6, kl = idx & 63;
        float x = T[nl][kl];
        ushort hb = bf16_rn(x);
        size_t o = (size_t)(n0 + nl) * K + k0 + kl;
        Thi[o] = hb;
        Tlo[o] = bf16_rn(x - bf16_f32(hb));
    }
}

__global__ __launch_bounds__(256)
void transpose_split(const float* __restrict__ W, ushort* __restrict__ Thi,
                     ushort* __restrict__ Tlo, int K, int N)
{
    __shared__ float T[64][65];
    const int k0 = blockIdx.y << 6, n0 = blockIdx.x << 6;
    const int tid = threadIdx.x;
    #pragma unroll
    for (int i = 0; i < 16; ++i) {
        int idx = tid + i * 256;
        int kl = idx >> 6, nl = idx & 63;
        T[nl][kl] = W[(size_t)(k0 + kl) * N + n0 + nl];
    }
    __syncthreads();
    #pragma unroll
    for (int i = 0; i < 16; ++i) {
        int idx = tid + i * 256;
        int nl = idx >> 6, kl = idx & 63;
        float x = T[nl][kl];
        ushort hb = bf16_rn(x);
        size_t o = (size_t)(n0 + nl) * K + k0 + kl;
        Thi[o] = hb;
        Tlo[o] = bf16_rn(x - bf16_f32(hb));
    }
}

// ---------------------------------------------------------------------------
// residual + LN: 4 rows per 256-thread block (one wave per row).
// ---------------------------------------------------------------------------
__global__ __launch_bounds__(256)
void ln_res(float* __restrict__ h, const float* __restrict__ t,
            const float* __restrict__ sc, const float* __restrict__ bi,
            ushort* __restrict__ hhi, ushort* __restrict__ hlo)
{
    const int row = blockIdx.x * 4 + (threadIdx.x >> 6);
    const int lane = threadIdx.x & 63;
    const size_t off = (size_t)row * D_ + (size_t)lane * 8;
    float x[8];
    float4 a0 = *(const float4*)(h + off),  a1 = *(const float4*)(h + off + 4);
    float4 b0 = *(const float4*)(t + off),  b1 = *(const float4*)(t + off + 4);
    x[0]=a0.x+b0.x; x[1]=a0.y+b0.y; x[2]=a0.z+b0.z; x[3]=a0.w+b0.w;
    x[4]=a1.x+b1.x; x[5]=a1.y+b1.y; x[6]=a1.z+b1.z; x[7]=a1.w+b1.w;

    float s = 0.f;
    #pragma unroll
    for (int i = 0; i < 8; ++i) s += x[i];
    #pragma unroll
    for (int d = 1; d < 64; d <<= 1) s += __shfl_xor(s, d);
    float mean = s * (1.0f / 512.0f);

    float vsum = 0.f;
    #pragma unroll
    for (int i = 0; i < 8; ++i) { float dx = x[i] - mean; vsum += dx * dx; }
    #pragma unroll
    for (int d = 1; d < 64; d <<= 1) vsum += __shfl_xor(vsum, d);
    float den = sqrtf(vsum * (1.0f / 512.0f) + 1e-5f);

    float4 s0 = *(const float4*)(sc + lane*8), s1 = *(const float4*)(sc + lane*8 + 4);
    float4 c0 = *(const float4*)(bi + lane*8), c1 = *(const float4*)(bi + lane*8 + 4);
    float scv[8] = {s0.x,s0.y,s0.z,s0.w,s1.x,s1.y,s1.z,s1.w};
    float biv[8] = {c0.x,c0.y,c0.z,c0.w,c1.x,c1.y,c1.z,c1.w};
    float out[8];
    ushort hh[8], ll[8];
    #pragma unroll
    for (int i = 0; i < 8; ++i) {
        out[i] = (x[i] - mean) / den * scv[i] + biv[i];
        hh[i] = bf16_rn(out[i]);
        ll[i] = bf16_rn(out[i] - bf16_f32(hh[i]));
    }
    *(float4*)(h + off)     = (float4){out[0],out[1],out[2],out[3]};
    *(float4*)(h + off + 4) = (float4){out[4],out[5],out[6],out[7]};
    *(ushort4*)(hhi + off)     = (ushort4){hh[0],hh[1],hh[2],hh[3]};
    *(ushort4*)(hhi + off + 4) = (ushort4){hh[4],hh[5],hh[6],hh[7]};
    *(ushort4*)(hlo + off)     = (ushort4){ll[0],ll[1],ll[2],ll[3]};
    *(ushort4*)(hlo + off + 4) = (ushort4){ll[4],ll[5],ll[6],ll[7]};
}

// ---------------------------------------------------------------------------
// z -> d_out copy + sq[token] = sum(z^2), fused. 4 rows/block.
// ---------------------------------------------------------------------------
__global__ __launch_bounds__(256)
void zout_sq(const float* __restrict__ z, float* __restrict__ outz,
             float* __restrict__ sq)
{
#pragma clang fp contract(off)
    const int row = blockIdx.x * 4 + (threadIdx.x >> 6);
    const int lane = threadIdx.x & 63;
    const size_t off = (size_t)row * D_ + (size_t)lane * 8;
    const float* p = z + off;
    float4 a0 = *(const float4*)(p), a1 = *(const float4*)(p + 4);
    float vv[8] = {a0.x,a0.y,a0.z,a0.w,a1.x,a1.y,a1.z,a1.w};
    float* op = outz + off;
    #pragma unroll
    for (int i = 0; i < 8; ++i) op[i] = vv[i];
    float s = 0.f;
    #pragma unroll
    for (int i = 0; i < 8; ++i) { float t = vv[i] * vv[i]; s = s + t; }
    #pragma unroll
    for (int d = 1; d < 64; d <<= 1) s += __shfl_xor(s, d);
    if (lane == 0) sq[row] = s;
}

__global__ __launch_bounds__(256)
void gram_kernel(const float* __restrict__ z, float* __restrict__ gram)
{
    __shared__ float Ls[16][68];
    const int s = blockIdx.x;
    const int tid = threadIdx.x;
    const int tx = tid & 15, ty = tid >> 4;
    const int arow = tid >> 2, ak4 = (tid & 3) << 2;
    float acc[4][4] = {};
    const float* zp = z + ((size_t)arow * S_ + s) * D_ + ak4;
    for (int k0 = 0; k0 < D_; k0 += 16) {
        float4 av = *(const float4*)(zp + k0);
        __syncthreads();
        Ls[ak4+0][arow] = av.x; Ls[ak4+1][arow] = av.y;
        Ls[ak4+2][arow] = av.z; Ls[ak4+3][arow] = av.w;
        __syncthreads();
        #pragma unroll
        for (int kk = 0; kk < 16; ++kk) {
            float4 a = *(const float4*)&Ls[kk][ty << 2];
            float4 b = *(const float4*)&Ls[kk][tx << 2];
            float ar[4] = {a.x,a.y,a.z,a.w};
            float br[4] = {b.x,b.y,b.z,b.w};
            #pragma unroll
            for (int i = 0; i < 4; ++i)
                #pragma unroll
                for (int j = 0; j < 4; ++j)
                    acc[i][j] = fmaf(ar[i], br[j], acc[i][j]);
        }
    }
    #pragma unroll
    for (int i = 0; i < 4; ++i) {
        float4 o = {acc[i][0], acc[i][1], acc[i][2], acc[i][3]};
        *(float4*)(gram + ((size_t)s * 64 + (ty<<2) + i) * 64 + (tx<<2)) = o;
    }
}

__global__ __launch_bounds__(64)
void cluster_kernel(const float* __restrict__ gram, const float* __restrict__ sq,
                    const int* __restrict__ y, float* __restrict__ contrib,
                    int* __restrict__ assigned, float* __restrict__ out_assigned_f)
{
#pragma clang fp contract(off)
    __shared__ float G[64][65];
    __shared__ float sqs[64];
    const int s = blockIdx.x, b = threadIdx.x;
    for (int i = b; i < 4096; i += 64)
        G[i >> 6][i & 63] = gram[(size_t)s * 4096 + i];
    sqs[b] = sq[(size_t)b * S_ + s];
    __syncthreads();

    const float sqb = sqs[b];
    float dmin = INFINITY, dsum = 0.f;
    for (int c = 0; c < 64; ++c) {
        float d = sqb + sqs[c] - 2.0f * G[b][c];
        dmin = fminf(dmin, d);
        dsum = dsum + d;
    }
    float Z = 0.f;
    for (int c = 0; c < 64; ++c) {
        float d = sqb + sqs[c] - 2.0f * G[b][c];
        float e = expf(dmin - d);
        G[b][c] = e;
        Z = Z + e;
    }
    for (int c = 0; c < 64; ++c) G[b][c] = G[b][c] / Z;

    int knn[16];
    #pragma unroll
    for (int j = 0; j < 16; ++j) {
        float bp = -1.f; int bi2 = 0;
        for (int c = 0; c < 64; ++c) {
            float pv = G[b][c];
            if (pv > bp) { bp = pv; bi2 = c; }
        }
        knn[j] = bi2;
        G[b][bi2] = -1.f;
    }
    int cmatch = 0;
    #pragma unroll
    for (int j = 0; j < 16; ++j) cmatch += (knn[j] == j) ? 1 : 0;
    int lab[16];
    #pragma unroll
    for (int j = 0; j < 16; ++j) lab[j] = y[knn[j] * S_ + s];
    int bestc = -1, bestcls = 0;
    #pragma unroll
    for (int cls = 0; cls < 16; ++cls) {
        int cc = 0;
        #pragma unroll
        for (int j = 0; j < 16; ++j) cc += (lab[j] == cls) ? 1 : 0;
        if (cc > bestc) { bestc = cc; bestcls = cls; }
    }
    const int oi = s * 64 + b;
    contrib[oi] = dsum * (float)cmatch;
    assigned[oi] = bestcls;
    out_assigned_f[oi] = (float)bestcls;
}

__global__ __launch_bounds__(256)
void finalize_kernel(const float* __restrict__ contrib, const int* __restrict__ assigned,
                     const int* __restrict__ y, float* __restrict__ dout)
{
#pragma clang fp contract(off)
    __shared__ int cm[256];
    __shared__ float red[256];
    const int tid = threadIdx.x;
    cm[tid] = 0;
    float s = 0.f;
    for (int i = tid; i < NTOK; i += 256) s = s + contrib[i];
    red[tid] = s;
    __syncthreads();
    for (int i = tid; i < NTOK; i += 256)
        atomicAdd(&cm[assigned[i] * 16 + y[i]], 1);
    __syncthreads();
    for (int st = 128; st > 0; st >>= 1) {
        if (tid < st) red[tid] = red[tid] + red[tid + st];
        __syncthreads();
    }
    if (tid == 0) {
        dout[0] = red[0];
        float sij = 0.f, sa = 0.f, sb = 0.f;
        for (int i = 0; i < 256; ++i) {
            float mm = (float)cm[i];
            sij = sij + mm * (mm - 1.0f) * 0.5f;
        }
        for (int r = 0; r < 16; ++r) {
            int rs = 0;
            for (int c2 = 0; c2 < 16; ++c2) rs += cm[r * 16 + c2];
            float mm = (float)rs;
            sa = sa + mm * (mm - 1.0f) * 0.5f;
        }
        for (int c2 = 0; c2 < 16; ++c2) {
            int cs = 0;
            for (int r = 0; r < 16; ++r) cs += cm[r * 16 + c2];
            float mm = (float)cs;
            sb = sb + mm * (mm - 1.0f) * 0.5f;
        }
        float n = 16384.0f;
        float expv = sa * sb / (n * (n - 1.0f) * 0.5f);
        float mx = 0.5f * (sa + sb);
        dout[1] = (sij - expv) / (mx - expv);
    }
}

// ---------------------------------------------------------------------------
extern "C" void kernel_launch(void* const* d_in, const int* in_sizes, int n_in,
                              void* d_out, int out_size, void* d_ws, size_t ws_size,
                              hipStream_t stream)
{
    (void)in_sizes; (void)n_in; (void)out_size; (void)ws_size;
    const float* x     = (const float*)d_in[0];
    const float* W_emb = (const float*)d_in[1];
    const float* b_emb = (const float*)d_in[2];
    const float* Wq    = (const float*)d_in[3];
    const float* bq    = (const float*)d_in[4];
    const float* Wk    = (const float*)d_in[5];
    const float* bk    = (const float*)d_in[6];
    const float* Wv    = (const float*)d_in[7];
    const float* bv    = (const float*)d_in[8];
    const float* Wo    = (const float*)d_in[9];
    const float* bo    = (const float*)d_in[10];
    const float* ln1_s = (const float*)d_in[11];
    const float* ln1_b = (const float*)d_in[12];
    const float* W1    = (const float*)d_in[13];
    const float* b1    = (const float*)d_in[14];
    const float* W2    = (const float*)d_in[15];
    const float* b2    = (const float*)d_in[16];
    const float* ln2_s = (const float*)d_in[17];
    const float* ln2_b = (const float*)d_in[18];
    const float* e1_w  = (const float*)d_in[19];
    const float* e1_b  = (const float*)d_in[20];
    const float* e2_w  = (const float*)d_in[21];
    const float* e2_b  = (const float*)d_in[22];
    const float* d1_w  = (const float*)d_in[23];
    const float* d1_b  = (const float*)d_in[24];
    const float* d2_w  = (const float*)d_in[25];
    const float* d2_b  = (const float*)d_in[26];
    const int*   y     = (const int*)d_in[27];

    float* ws = (float*)d_ws;
    float*  h    = ws;                                   // 8388608
    ushort* hhi  = (ushort*)(ws + 8388608);
    ushort* hlo  = (ushort*)(ws + 12582912);
    float*  SCR  = ws + 16777216;                        // 20971520 slots scratch
    ushort* obhi = (ushort*)(ws + 37748736);
    ushort* oblo = (ushort*)(ws + 41943040);
    float*  wt   = ws + 46137344;
    ushort* WTQKV_HI = (ushort*)wt;
    ushort* WTQKV_LO = WTQKV_HI + 786432;
    ushort* WTO_HI   = WTQKV_LO + 786432;
    ushort* WTO_LO   = WTO_HI + 262144;
    ushort* WT1_HI   = WTO_LO + 262144;
    ushort* WT1_LO   = WT1_HI + 1048576;
    ushort* WT2_HI   = WT1_LO + 1048576;
    ushort* WT2_LO   = WT2_HI + 1048576;
    ushort* WE1_HI   = WT2_LO + 1048576;
    ushort* WE1_LO   = WE1_HI + 65536;
    ushort* WE2_HI   = WE1_LO + 65536;
    ushort* WE2_LO   = WE2_HI + 65536;
    ushort* WD1_HI   = WE2_LO + 65536;
    ushort* WD1_LO   = WD1_HI + 65536;
    ushort* WD2_HI   = WD1_LO + 65536;
    ushort* WD2_LO   = WD2_HI + 65536;
    float*  biasqkv  = ws + 49545216;

    // attention-phase overlays
    ushort* Phi_  = (ushort*)SCR;
    ushort* Plo_  = (ushort*)(SCR + 4194304);
    ushort* qkvhi = (ushort*)(SCR + 8388608);
    ushort* qkvlo = (ushort*)(SCR + 11534336);
    ushort* VThi  = (ushort*)(SCR + 14680064);
    ushort* VTlo  = (ushort*)(SCR + 15728640);
    // post-attention / FFN phase:
    float*  Of32  = SCR;
    ushort* f1hi  = (ushort*)SCR;
    ushort* f1lo  = (ushort*)(SCR + 8388608);
    float*  Xhalf = SCR + 16777216;
    // cluster phase:
    ushort* enchi = (ushort*)SCR;
    ushort* enclo = (ushort*)(SCR + 4194304);
    float*  z     = SCR + 8388608;
    float*  gram  = SCR + 16777216;
    float*  sqb_  = SCR + 17825792;
    float*  contrib = SCR + 17842176;
    int*    assigned = (int*)(SCR + 17858560);
    ushort* t1hi = obhi;
    ushort* t1lo = oblo;
    ushort* t2hi = obhi + 2097152;
    ushort* t2lo = oblo + 2097152;
    float*  dout = (float*)d_out;

    dim3 blk(256);
    auto gg = [](int M, int N) { return dim3(N >> 7, M >> 7); };

    transpose_split<<<dim3(2, 8), blk, 0, stream>>>(e1_w, WE1_HI, WE1_LO, 512, 128);
    transpose_split<<<dim3(8, 2), blk, 0, stream>>>(e2_w, WE2_HI, WE2_LO, 128, 512);
    transpose_split<<<dim3(2, 8), blk, 0, stream>>>(d1_w, WD1_HI, WD1_LO, 512, 128);
    transpose_split<<<dim3(8, 2), blk, 0, stream>>>(d2_w, WD2_HI, WD2_LO, 128, 512);

    gemm_f32<<<dim3(8, 256), blk, 0, stream>>>(x, W_emb, b_emb, h, hhi, hlo, NTOK, D_, IN_);

    for (int l = 0; l < L_; ++l) {
        prep_layer<<<dim3(774), blk, 0, stream>>>(
            Wq + (size_t)l*D_*D_, Wk + (size_t)l*D_*D_, Wv + (size_t)l*D_*D_,
            Wo + (size_t)l*D_*D_, W1 + (size_t)l*D_*DFF_, W2 + (size_t)l*DFF_*D_,
            bq + l*D_, bk + l*D_, bv + l*D_,
            WTQKV_HI, WTQKV_LO, WTO_HI, WTO_LO, WT1_HI, WT1_LO, WT2_HI, WT2_LO,
            biasqkv);

        for (int qtr = 0; qtr < 4; ++qtr) {
            const size_t hoff = (size_t)qtr * 4096 * 512;
            gemm3<2><<<gg(4096, 1536), blk, 0, stream>>>(
                hhi + hoff, hlo + hoff, WTQKV_HI, WTQKV_LO, biasqkv,
                nullptr, qkvhi, qkvlo, 4096, 1536, 512);
            qks_gemm<<<dim3(2, 128), blk, 0, stream>>>(qkvhi, qkvlo, Phi_, Plo_,
                                                       VThi, VTlo);
            pv_gemm<<<dim3(2, 128), blk, 0, stream>>>(Phi_, Plo_, VThi, VTlo,
                                                      obhi, oblo, qtr * 4096);
        }
        gemm3<0><<<gg(NTOK, 512), blk, 0, stream>>>(
            obhi, oblo, WTO_HI, WTO_LO, bo + l*D_,
            Of32, nullptr, nullptr, NTOK, 512, 512);
        ln_res<<<dim3(NTOK / 4), blk, 0, stream>>>(h, Of32, ln1_s + l*D_, ln1_b + l*D_, hhi, hlo);

        for (int half = 0; half < 2; ++half) {
            const size_t ro = (size_t)half * HALF_ * D_;
            gemm3<3><<<gg(HALF_, DFF_), blk, 0, stream>>>(
                hhi + ro, hlo + ro, WT1_HI, WT1_LO, b1 + l*DFF_,
                nullptr, f1hi, f1lo, HALF_, 2048, 512);
            gemm3<0><<<gg(HALF_, 512), blk, 0, stream>>>(
                f1hi, f1lo, WT2_HI, WT2_LO, b2 + l*D_,
                Xhalf, nullptr, nullptr, HALF_, 512, 2048);
            ln_res<<<dim3(HALF_ / 4), blk, 0, stream>>>(
                h + ro, Xhalf, ln2_s + l*D_, ln2_b + l*D_, hhi + ro, hlo + ro);
        }
    }

    gemm3_n128<<<dim3(256), blk, 0, stream>>>(
        hhi, hlo, WE1_HI, WE1_LO, e1_b, t1hi, t1lo, NTOK);
    gemm3<2><<<gg(NTOK, 512), blk, 0, stream>>>(
        t1hi, t1lo, WE2_HI, WE2_LO, e2_b, nullptr, enchi, enclo, NTOK, 512, 128);
    gemm3_n128<<<dim3(256), blk, 0, stream>>>(
        enchi, enclo, WD1_HI, WD1_LO, d1_b, t2hi, t2lo, NTOK);
    gemm3<0><<<gg(NTOK, 512), blk, 0, stream>>>(
        t2hi, t2lo, WD2_HI, WD2_LO, d2_b, z, nullptr, nullptr, NTOK, 512, 128);

    zout_sq<<<dim3(NTOK / 4), blk, 0, stream>>>(z, dout + 16386, sqb_);
    gram_kernel<<<dim3(S_), blk, 0, stream>>>(z, gram);
    cluster_kernel<<<dim3(S_), dim3(64), 0, stream>>>(gram, sqb_, y, contrib, assigned, dout + 2);
    finalize_kernel<<<dim3(1), blk, 0, stream>>>(contrib, assigned, y, dout);
}